// Round 8
// baseline (416.550 us; speedup 1.0000x reference)
//
#include <hip/hip_runtime.h>
#include <hip/hip_bf16.h>

// Problem constants (MambaBlock): B=2, L=2048, d_model=1024, d_inner=2048,
// d_conv=4, dt_rank=64, d_state=16. All inputs/output float32 (per reference).

#define BATCH   2
#define SEQLEN  2048
#define DMODEL  1024
#define DINNER  2048
#define DCONV   4
#define DTRANK  64
#define DSTATE  16
#define BL      (BATCH * SEQLEN)         // 4096
#define NXZ     (2 * DINNER)             // 4096
#define XDBL_N  (DTRANK + 2 * DSTATE)    // 96
#define LCH     64                       // chunk length for parallel scan
#define NCHUNK  (SEQLEN / LCH)           // 32 chunks per sequence
#define KSPLIT  8                        // split-K for the x_dbl GEMM
#define KC      (DINNER / KSPLIT)        // 256

typedef __bf16 bf16x8 __attribute__((ext_vector_type(8)));
typedef __bf16 bf16x4 __attribute__((ext_vector_type(4)));
typedef float  floatx4 __attribute__((ext_vector_type(4)));

__device__ __forceinline__ float silu_f(float v) {
    return v / (1.f + __expf(-v));
}

// Fast softplus via native v_exp_f32/v_log_f32 (error ~1e-7, << bf16 noise).
__device__ __forceinline__ float softplus_f(float v) {
    return (v > 20.f) ? v : __logf(1.f + __expf(v));
}

__device__ __forceinline__ void gload_lds16(const __bf16* g, __bf16* l) {
    __builtin_amdgcn_global_load_lds(
        (const __attribute__((address_space(1))) void*)g,
        (__attribute__((address_space(3))) void*)l, 16, 0, 0);
}

// ---------------------------------------------------------------------------
// MFMA bf16 GEMM (m97 structure): C[M,N] = A[M,K] * B[K,N].
// A [M,K] bf16 row-major; BT [N,K] bf16 row-major.
// EPI: 0 = fp32 store; 1 = softplus(acc+bias[col]) fp32; 2 = bf16 store.
// ---------------------------------------------------------------------------
template <int EPI>
__global__ __launch_bounds__(256) void gemm_bt_mfma(
    const __bf16* __restrict__ A,
    const __bf16* __restrict__ BT,
    void* __restrict__ Cv,
    int M, int N, int K,
    const float* __restrict__ bias)
{
    __shared__ __bf16 Asm[128 * 32];
    __shared__ __bf16 Bsm[128 * 32];

    const int tid  = threadIdx.x;
    const int w    = tid >> 6;
    const int lane = tid & 63;
    const int lrow = lane & 15;
    const int quad = lane >> 4;
    const int row0 = blockIdx.y * 128;
    const int col0 = blockIdx.x * 128;
    const int wr   = (w >> 1) * 64;
    const int wc   = (w & 1) * 64;

    const int ldr = tid >> 2;
    const int ldk = (tid & 3) * 8;
    const __bf16* gA = A  + (size_t)(row0 + ldr) * K + ldk;
    const __bf16* gB = BT + (size_t)(col0 + ldr) * K + ldk;
    const size_t half = (size_t)64 * K;
    __bf16* lA0 = Asm + w * 512;
    __bf16* lA1 = Asm + 2048 + w * 512;
    __bf16* lB0 = Bsm + w * 512;
    __bf16* lB1 = Bsm + 2048 + w * 512;

    floatx4 acc[4][4];
#pragma unroll
    for (int i = 0; i < 4; ++i)
#pragma unroll
        for (int j = 0; j < 4; ++j)
            acc[i][j] = (floatx4){0.f, 0.f, 0.f, 0.f};

    for (int k0 = 0; k0 < K; k0 += 32) {
        gload_lds16(gA, lA0);
        gload_lds16(gA + half, lA1);
        gload_lds16(gB, lB0);
        gload_lds16(gB + half, lB1);
        gA += 32; gB += 32;
        __syncthreads();

        bf16x8 af[4], bf[4];
#pragma unroll
        for (int t = 0; t < 4; ++t)
            af[t] = *(const bf16x8*)(Asm + (wr + t * 16 + lrow) * 32 + quad * 8);
#pragma unroll
        for (int t = 0; t < 4; ++t)
            bf[t] = *(const bf16x8*)(Bsm + (wc + t * 16 + lrow) * 32 + quad * 8);

#pragma unroll
        for (int ti = 0; ti < 4; ++ti)
#pragma unroll
            for (int tj = 0; tj < 4; ++tj)
                acc[ti][tj] = __builtin_amdgcn_mfma_f32_16x16x32_bf16(
                    af[ti], bf[tj], acc[ti][tj], 0, 0, 0);
        __syncthreads();
    }

#pragma unroll
    for (int ti = 0; ti < 4; ++ti) {
#pragma unroll
        for (int tj = 0; tj < 4; ++tj) {
            int col = col0 + wc + tj * 16 + lrow;
            float bv = (EPI == 1) ? bias[col] : 0.f;
#pragma unroll
            for (int r = 0; r < 4; ++r) {
                int row = row0 + wr + ti * 16 + quad * 4 + r;
                float v = acc[ti][tj][r];
                if (EPI == 1) v = softplus_f(v + bv);
                if (EPI == 2)
                    ((__bf16*)Cv)[(size_t)row * N + col] = (__bf16)v;
                else
                    ((float*)Cv)[(size_t)row * N + col] = v;
            }
        }
    }
}

// ---------------------------------------------------------------------------
// fp32 -> bf16 cast (vectorized 4/thread).
// ---------------------------------------------------------------------------
__global__ __launch_bounds__(256) void cast_bf16_kernel(
    const float* __restrict__ src, __bf16* __restrict__ dst, long n)
{
    long i = ((long)blockIdx.x * 256 + threadIdx.x) * 4;
    if (i >= n) return;
    float4 v = *(const float4*)(src + i);
    bf16x4 o = {(__bf16)v.x, (__bf16)v.y, (__bf16)v.z, (__bf16)v.w};
    *(bf16x4*)(dst + i) = o;
}

// ---------------------------------------------------------------------------
// Transpose-cast: src fp32 [R,Cc] -> dst bf16 [Cc,R]. R,Cc multiples of 32.
// ---------------------------------------------------------------------------
__global__ __launch_bounds__(256) void transpose_cast(
    const float* __restrict__ src, __bf16* __restrict__ dst, int R, int Cc)
{
    __shared__ float tile[32][33];
    int c0 = blockIdx.x * 32, r0 = blockIdx.y * 32;
    int tx = threadIdx.x, ty = threadIdx.y;   // 32 x 8
#pragma unroll
    for (int i = 0; i < 32; i += 8)
        tile[ty + i][tx] = src[(size_t)(r0 + ty + i) * Cc + c0 + tx];
    __syncthreads();
#pragma unroll
    for (int i = 0; i < 32; i += 8)
        dst[(size_t)(c0 + ty + i) * R + r0 + tx] = (__bf16)tile[tx][ty + i];
}

// ---------------------------------------------------------------------------
// Causal depthwise conv (d_conv=4) + SiLU, bf16 in/out, 8 channels/thread.
// xb = xz16[:, 0:DINNER] (stride NXZ).
// ---------------------------------------------------------------------------
__global__ __launch_bounds__(256) void conv_silu_kernel(
    const __bf16* __restrict__ xz16,
    const float* __restrict__ cw,    // [DINNER, 4]
    const float* __restrict__ cb,    // [DINNER]
    __bf16* __restrict__ xc16)       // [BL, DINNER]
{
    long i = ((long)blockIdx.x * 256 + threadIdx.x) * 8;   // over BL*DINNER
    long r = i / DINNER;
    int d = (int)(i % DINNER);
    int t = (int)(r % SEQLEN);

    float acc[8];
    {
        float4 b0 = *(const float4*)(cb + d);
        float4 b1 = *(const float4*)(cb + d + 4);
        acc[0]=b0.x; acc[1]=b0.y; acc[2]=b0.z; acc[3]=b0.w;
        acc[4]=b1.x; acc[5]=b1.y; acc[6]=b1.z; acc[7]=b1.w;
    }
#pragma unroll
    for (int k = 0; k < DCONV; ++k) {
        int tt = t - (DCONV - 1) + k;
        if (tt < 0) continue;
        bf16x8 v = *(const bf16x8*)(xz16 + (r - (DCONV - 1) + k) * NXZ + d);
#pragma unroll
        for (int j = 0; j < 8; ++j)
            acc[j] += (float)v[j] * cw[(d + j) * DCONV + k];
    }
    bf16x8 o;
#pragma unroll
    for (int j = 0; j < 8; ++j)
        o[j] = (__bf16)silu_f(acc[j]);
    *(bf16x8*)(xc16 + i) = o;
}

// ---------------------------------------------------------------------------
// Split-K GEMM for x_dbl: A[4096,2048] bf16 * W[2048,96] fp32 -> partials.
// Block: 64 rows x 96 cols x KC=256; grid (M/64, KSPLIT).
// ---------------------------------------------------------------------------
__global__ __launch_bounds__(256) void gemm_xdbl_split(
    const __bf16* __restrict__ A,    // [BL, DINNER] bf16
    const float* __restrict__ W,     // [DINNER, 96]
    float* __restrict__ parts)       // [KSPLIT, BL, 96]
{
    __shared__ float As[16][65];
    __shared__ float Bs[16][97];

    const int tid  = threadIdx.x;
    const int row0 = blockIdx.x * 64;
    const int kz   = blockIdx.y;
    const int kbeg = kz * KC;

    const int tr = tid >> 4;
    const int tc = tid & 15;

    const int arow = tid >> 2;
    const int akq  = (tid & 3) * 4;
    const int brow = tid >> 4;
    const int bcol = (tid & 15) * 6;

    float acc[4][6] = {};

    for (int k0 = kbeg; k0 < kbeg + KC; k0 += 16) {
        {
            bf16x4 v = *(const bf16x4*)(A + (size_t)(row0 + arow) * DINNER + k0 + akq);
            As[akq + 0][arow] = (float)v[0];
            As[akq + 1][arow] = (float)v[1];
            As[akq + 2][arow] = (float)v[2];
            As[akq + 3][arow] = (float)v[3];
        }
#pragma unroll
        for (int j = 0; j < 6; ++j)
            Bs[brow][bcol + j] = W[(size_t)(k0 + brow) * XDBL_N + bcol + j];
        __syncthreads();

#pragma unroll
        for (int kk = 0; kk < 16; ++kk) {
            float a[4], b[6];
#pragma unroll
            for (int i = 0; i < 4; ++i) a[i] = As[kk][tr * 4 + i];
#pragma unroll
            for (int j = 0; j < 6; ++j) b[j] = Bs[kk][tc * 6 + j];
#pragma unroll
            for (int i = 0; i < 4; ++i)
#pragma unroll
                for (int j = 0; j < 6; ++j)
                    acc[i][j] += a[i] * b[j];
        }
        __syncthreads();
    }

    const long base = (long)kz * BL * XDBL_N;
#pragma unroll
    for (int i = 0; i < 4; ++i) {
        long off = base + (long)(row0 + tr * 4 + i) * XDBL_N + tc * 6;
#pragma unroll
        for (int j = 0; j < 6; ++j)
            parts[off + j] = acc[i][j];
    }
}

// Reduce KSPLIT partials -> xdbl [BL, 96]; cols<64 also stored bf16 (dt_low).
__global__ __launch_bounds__(256) void xdbl_reduce(
    const float* __restrict__ parts, float* __restrict__ xdbl,
    __bf16* __restrict__ dtlow16)
{
    long i = (long)blockIdx.x * 256 + threadIdx.x;   // < BL*96
    float s = 0.f;
#pragma unroll
    for (int kz = 0; kz < KSPLIT; ++kz)
        s += parts[(long)kz * BL * XDBL_N + i];
    xdbl[i] = s;
    int col = (int)(i % XDBL_N);
    if (col < DTRANK) {
        long row = i / XDBL_N;
        dtlow16[row * DTRANK + col] = (__bf16)s;
    }
}

// ---------------------------------------------------------------------------
// Chunked parallel scan. Summaries in dedicated scratch:
//   sums_h[(bc*16+n)*DINNER + d], sums_p same layout (P, then hstart).
// ---------------------------------------------------------------------------
__global__ __launch_bounds__(256) void scan_pass1(
    const float* __restrict__ dt,
    const __bf16* __restrict__ xc16,
    const float* __restrict__ xdbl,
    const float* __restrict__ A_log,
    float* __restrict__ sums_h,
    float* __restrict__ sums_p)
{
    const int d  = blockIdx.x * 256 + threadIdx.x;
    const int bc = blockIdx.y;
    const int b  = bc / NCHUNK, c = bc % NCHUNK;
    const long r0 = (long)b * SEQLEN + (long)c * LCH;

    float Ad[DSTATE];
    {
        const float4* al = (const float4*)(A_log + d * DSTATE);
#pragma unroll
        for (int q = 0; q < 4; ++q) {
            float4 v = al[q];
            Ad[q * 4 + 0] = -__expf(v.x); Ad[q * 4 + 1] = -__expf(v.y);
            Ad[q * 4 + 2] = -__expf(v.z); Ad[q * 4 + 3] = -__expf(v.w);
        }
    }

    float h[DSTATE] = {};
    float Pp[DSTATE];
#pragma unroll
    for (int n = 0; n < DSTATE; ++n) Pp[n] = 1.f;

    for (int t = 0; t < LCH; ++t) {
        long r = r0 + t;
        float dtv = dt[r * DINNER + d];
        float xv  = (float)xc16[r * DINNER + d];
        float xdt = xv * dtv;
        const float4* bv = (const float4*)(xdbl + r * XDBL_N + DTRANK);
        float4 B0 = bv[0], B1 = bv[1], B2 = bv[2], B3 = bv[3];
        const float Bn[DSTATE] = {B0.x,B0.y,B0.z,B0.w, B1.x,B1.y,B1.z,B1.w,
                                  B2.x,B2.y,B2.z,B2.w, B3.x,B3.y,B3.z,B3.w};
#pragma unroll
        for (int n = 0; n < DSTATE; ++n) {
            float dA = __expf(Ad[n] * dtv);
            h[n] = h[n] * dA + xdt * Bn[n];
            Pp[n] *= dA;
        }
    }

    const long rowbase = (long)bc * DSTATE;
#pragma unroll
    for (int n = 0; n < DSTATE; ++n) {
        sums_h[(rowbase + n) * DINNER + d] = h[n];
        sums_p[(rowbase + n) * DINNER + d] = Pp[n];
    }
}

__global__ __launch_bounds__(256) void scan_combine(
    float* __restrict__ sums_h, float* __restrict__ sums_p)
{
    int u = blockIdx.x * 256 + threadIdx.x;
    int d = u & (DINNER - 1);
    int n = (u >> 11) & (DSTATE - 1);
    int b = u >> 15;
    float hg = 0.f;
    for (int c = 0; c < NCHUNK; ++c) {
        long row = (long)(b * NCHUNK + c) * DSTATE + n;
        float p  = sums_p[row * DINNER + d];
        float hl = sums_h[row * DINNER + d];
        sums_p[row * DINNER + d] = hg;   // hstart for this chunk
        hg = p * hg + hl;
    }
}

// Pass 3: replay from hstart, fused gate, emit bf16 gated activation.
__global__ __launch_bounds__(256) void scan_pass3(
    const float* __restrict__ dt,
    const __bf16* __restrict__ xc16,
    const float* __restrict__ xdbl,
    const float* __restrict__ A_log,
    const __bf16* __restrict__ xz16,  // z half at col DINNER+d
    const float* __restrict__ sums_p, // hstart
    const float* __restrict__ Dp,
    __bf16* __restrict__ gated)       // [BL, DINNER] bf16
{
    const int d  = blockIdx.x * 256 + threadIdx.x;
    const int bc = blockIdx.y;
    const int b  = bc / NCHUNK, c = bc % NCHUNK;
    const long r0 = (long)b * SEQLEN + (long)c * LCH;

    float Ad[DSTATE];
    {
        const float4* al = (const float4*)(A_log + d * DSTATE);
#pragma unroll
        for (int q = 0; q < 4; ++q) {
            float4 v = al[q];
            Ad[q * 4 + 0] = -__expf(v.x); Ad[q * 4 + 1] = -__expf(v.y);
            Ad[q * 4 + 2] = -__expf(v.z); Ad[q * 4 + 3] = -__expf(v.w);
        }
    }

    float h[DSTATE];
    const long rowbase = (long)bc * DSTATE;
#pragma unroll
    for (int n = 0; n < DSTATE; ++n)
        h[n] = sums_p[(rowbase + n) * DINNER + d];

    const float Dv = Dp[d];

    for (int t = 0; t < LCH; ++t) {
        long r = r0 + t;
        float dtv = dt[r * DINNER + d];
        float xv  = (float)xc16[r * DINNER + d];
        float xdt = xv * dtv;
        const float4* bv = (const float4*)(xdbl + r * XDBL_N + DTRANK);
        float4 B0 = bv[0], B1 = bv[1], B2 = bv[2], B3 = bv[3];
        float4 C0 = bv[4], C1 = bv[5], C2 = bv[6], C3 = bv[7];
        const float Bn[DSTATE] = {B0.x,B0.y,B0.z,B0.w, B1.x,B1.y,B1.z,B1.w,
                                  B2.x,B2.y,B2.z,B2.w, B3.x,B3.y,B3.z,B3.w};
        const float Cn[DSTATE] = {C0.x,C0.y,C0.z,C0.w, C1.x,C1.y,C1.z,C1.w,
                                  C2.x,C2.y,C2.z,C2.w, C3.x,C3.y,C3.z,C3.w};
        float y = 0.f;
#pragma unroll
        for (int n = 0; n < DSTATE; ++n) {
            float dA = __expf(Ad[n] * dtv);
            h[n] = h[n] * dA + xdt * Bn[n];
            y += h[n] * Cn[n];
        }
        float z = (float)xz16[r * NXZ + DINNER + d];
        float yy = y + xv * Dv;
        gated[r * DINNER + d] = (__bf16)(yy * silu_f(z));
    }
}

// ---------------------------------------------------------------------------
extern "C" void kernel_launch(void* const* d_in, const int* in_sizes, int n_in,
                              void* d_out, int out_size, void* d_ws, size_t ws_size,
                              hipStream_t stream) {
    const float* x      = (const float*)d_in[0];  // [B,L,DMODEL]
    const float* W_in   = (const float*)d_in[1];  // [DMODEL, NXZ]
    const float* conv_w = (const float*)d_in[2];  // [DINNER, 4]
    const float* conv_b = (const float*)d_in[3];  // [DINNER]
    const float* W_x    = (const float*)d_in[4];  // [DINNER, 96]
    const float* W_dt   = (const float*)d_in[5];  // [DTRANK, DINNER]
    const float* b_dt   = (const float*)d_in[6];  // [DINNER]
    const float* A_log  = (const float*)d_in[7];  // [DINNER, 16]
    const float* Dp     = (const float*)d_in[8];  // [DINNER]
    const float* W_out  = (const float*)d_in[9];  // [DINNER, DMODEL]
    float* out = (float*)d_out;                   // [B,L,DMODEL]

    // Workspace layout (all distinct, ~141 MB total):
    __bf16* xz16    = (__bf16*)d_ws;                    // BL*NXZ       (33.5 MB)
    __bf16* xc16    = xz16 + (long)BL * NXZ;            // BL*DINNER    (16.8 MB)
    float*  xdbl    = (float*)(xc16 + (long)BL * DINNER);   // BL*96    ( 1.6 MB)
    float*  dt      = xdbl + (long)BL * XDBL_N;         // BL*DINNER    (33.5 MB)
    __bf16* gated16 = (__bf16*)(dt + (long)BL * DINNER);    // BL*DINNER(16.8 MB)
    __bf16* WoT16   = gated16 + (long)BL * DINNER;      // DINNER*DMODEL( 4.2 MB)
    __bf16* WdtT16  = WoT16 + (long)DINNER * DMODEL;    // DINNER*64    ( 0.3 MB)
    __bf16* dtlow16 = WdtT16 + (long)DINNER * DTRANK;   // BL*64        ( 0.5 MB)
    __bf16* xb16    = dtlow16 + (long)BL * DTRANK;      // BL*DMODEL    ( 8.4 MB)
    __bf16* WiT16   = xb16 + (long)BL * DMODEL;         // NXZ*DMODEL   ( 8.4 MB)
    float*  scratch = (float*)(WiT16 + (long)NXZ * DMODEL); // max(partials 12.6, sums 16.8 MB)
    float*  sums_h  = scratch;                          // 1024*DINNER  ( 8.4 MB)
    float*  sums_p  = scratch + (long)BATCH * NCHUNK * DSTATE * DINNER; // 8.4 MB

    dim3 blk(256);

    // 0) casts: x -> bf16; W_in -> bf16^T; W_out -> bf16^T; W_dt -> bf16^T
    cast_bf16_kernel<<<dim3((BL * DMODEL / 4) / 256), blk, 0, stream>>>(
        x, xb16, (long)BL * DMODEL);
    transpose_cast<<<dim3(NXZ / 32, DMODEL / 32), dim3(32, 8), 0, stream>>>(
        W_in, WiT16, DMODEL, NXZ);
    transpose_cast<<<dim3(DMODEL / 32, DINNER / 32), dim3(32, 8), 0, stream>>>(
        W_out, WoT16, DINNER, DMODEL);
    transpose_cast<<<dim3(DINNER / 32, DTRANK / 32), dim3(32, 8), 0, stream>>>(
        W_dt, WdtT16, DTRANK, DINNER);

    // 1) xz = x @ W_in   (MFMA bf16, bf16 store)
    gemm_bt_mfma<2><<<dim3(NXZ / 128, BL / 128), blk, 0, stream>>>(
        xb16, WiT16, xz16, BL, NXZ, DMODEL, nullptr);

    // 2) causal depthwise conv + silu -> xc16 (bf16, 8 ch/thread)
    conv_silu_kernel<<<dim3((BL * DINNER / 8) / 256), blk, 0, stream>>>(
        xz16, conv_w, conv_b, xc16);

    // 3) x_dbl = xc @ W_x   (split-K, bf16 A; partials in scratch)
    gemm_xdbl_split<<<dim3(BL / 64, KSPLIT), blk, 0, stream>>>(xc16, W_x, scratch);
    xdbl_reduce<<<dim3((BL * XDBL_N) / 256), blk, 0, stream>>>(scratch, xdbl, dtlow16);

    // 4) dt = softplus(dt_low @ W_dt + b_dt)   (MFMA bf16, fp32 out)
    gemm_bt_mfma<1><<<dim3(DINNER / 128, BL / 128), blk, 0, stream>>>(
        dtlow16, WdtT16, dt, BL, DINNER, DTRANK, b_dt);

    // 5) chunked scan: pass1 -> combine -> pass3 (+fused gate, bf16 out)
    {
        dim3 grid1(DINNER / 256, BATCH * NCHUNK);
        scan_pass1<<<grid1, blk, 0, stream>>>(dt, xc16, xdbl, A_log, sums_h, sums_p);
        scan_combine<<<dim3((BATCH * DSTATE * DINNER) / 256), blk, 0, stream>>>(
            sums_h, sums_p);
        scan_pass3<<<grid1, blk, 0, stream>>>(dt, xc16, xdbl, A_log, xz16,
                                              sums_p, Dp, gated16);
    }
    // 7) out = gated @ W_out   (MFMA bf16, fp32 out)
    gemm_bt_mfma<0><<<dim3(DMODEL / 128, BL / 128), blk, 0, stream>>>(
        gated16, WoT16, out, BL, DMODEL, DINNER, nullptr);

    (void)in_sizes; (void)n_in; (void)out_size; (void)ws_size;
}

// Round 9
// 369.791 us; speedup vs baseline: 1.1264x; 1.1264x over previous
//
#include <hip/hip_runtime.h>
#include <hip/hip_bf16.h>

// Problem constants (MambaBlock): B=2, L=2048, d_model=1024, d_inner=2048,
// d_conv=4, dt_rank=64, d_state=16. All inputs/output float32 (per reference).

#define BATCH   2
#define SEQLEN  2048
#define DMODEL  1024
#define DINNER  2048
#define DCONV   4
#define DTRANK  64
#define DSTATE  16
#define BL      (BATCH * SEQLEN)         // 4096
#define NXZ     (2 * DINNER)             // 4096
#define XDBL_N  (DTRANK + 2 * DSTATE)    // 96
#define LCH     64                       // chunk length for parallel scan
#define NCHUNK  (SEQLEN / LCH)           // 32 chunks per sequence
#define KSPLIT  8                        // split-K for the x_dbl GEMM
#define KC      (DINNER / KSPLIT)        // 256
#define CONVT   8                        // rows per conv block

typedef __bf16 bf16x8 __attribute__((ext_vector_type(8)));
typedef __bf16 bf16x4 __attribute__((ext_vector_type(4)));
typedef float  floatx4 __attribute__((ext_vector_type(4)));

__device__ __forceinline__ float silu_f(float v) {
    return v / (1.f + __expf(-v));
}

// Fast softplus via native v_exp_f32/v_log_f32 (error ~1e-7, << bf16 noise).
__device__ __forceinline__ float softplus_f(float v) {
    return (v > 20.f) ? v : __logf(1.f + __expf(v));
}

__device__ __forceinline__ void gload_lds16(const __bf16* g, __bf16* l) {
    __builtin_amdgcn_global_load_lds(
        (const __attribute__((address_space(1))) void*)g,
        (__attribute__((address_space(3))) void*)l, 16, 0, 0);
}

// ---------------------------------------------------------------------------
// MFMA bf16 GEMM (m97 structure): C[M,N] = A[M,K] * B[K,N].
// A [M,K] bf16 row-major; BT [N,K] bf16 row-major.
// EPI: 0 = fp32 store; 1 = softplus(acc+bias[col]) fp32; 2 = bf16 store.
// ---------------------------------------------------------------------------
template <int EPI>
__global__ __launch_bounds__(256) void gemm_bt_mfma(
    const __bf16* __restrict__ A,
    const __bf16* __restrict__ BT,
    void* __restrict__ Cv,
    int M, int N, int K,
    const float* __restrict__ bias)
{
    __shared__ __bf16 Asm[128 * 32];
    __shared__ __bf16 Bsm[128 * 32];

    const int tid  = threadIdx.x;
    const int w    = tid >> 6;
    const int lane = tid & 63;
    const int lrow = lane & 15;
    const int quad = lane >> 4;
    const int row0 = blockIdx.y * 128;
    const int col0 = blockIdx.x * 128;
    const int wr   = (w >> 1) * 64;
    const int wc   = (w & 1) * 64;

    const int ldr = tid >> 2;
    const int ldk = (tid & 3) * 8;
    const __bf16* gA = A  + (size_t)(row0 + ldr) * K + ldk;
    const __bf16* gB = BT + (size_t)(col0 + ldr) * K + ldk;
    const size_t half = (size_t)64 * K;
    __bf16* lA0 = Asm + w * 512;
    __bf16* lA1 = Asm + 2048 + w * 512;
    __bf16* lB0 = Bsm + w * 512;
    __bf16* lB1 = Bsm + 2048 + w * 512;

    floatx4 acc[4][4];
#pragma unroll
    for (int i = 0; i < 4; ++i)
#pragma unroll
        for (int j = 0; j < 4; ++j)
            acc[i][j] = (floatx4){0.f, 0.f, 0.f, 0.f};

    for (int k0 = 0; k0 < K; k0 += 32) {
        gload_lds16(gA, lA0);
        gload_lds16(gA + half, lA1);
        gload_lds16(gB, lB0);
        gload_lds16(gB + half, lB1);
        gA += 32; gB += 32;
        __syncthreads();

        bf16x8 af[4], bf[4];
#pragma unroll
        for (int t = 0; t < 4; ++t)
            af[t] = *(const bf16x8*)(Asm + (wr + t * 16 + lrow) * 32 + quad * 8);
#pragma unroll
        for (int t = 0; t < 4; ++t)
            bf[t] = *(const bf16x8*)(Bsm + (wc + t * 16 + lrow) * 32 + quad * 8);

#pragma unroll
        for (int ti = 0; ti < 4; ++ti)
#pragma unroll
            for (int tj = 0; tj < 4; ++tj)
                acc[ti][tj] = __builtin_amdgcn_mfma_f32_16x16x32_bf16(
                    af[ti], bf[tj], acc[ti][tj], 0, 0, 0);
        __syncthreads();
    }

#pragma unroll
    for (int ti = 0; ti < 4; ++ti) {
#pragma unroll
        for (int tj = 0; tj < 4; ++tj) {
            int col = col0 + wc + tj * 16 + lrow;
            float bv = (EPI == 1) ? bias[col] : 0.f;
#pragma unroll
            for (int r = 0; r < 4; ++r) {
                int row = row0 + wr + ti * 16 + quad * 4 + r;
                float v = acc[ti][tj][r];
                if (EPI == 1) v = softplus_f(v + bv);
                if (EPI == 2)
                    ((__bf16*)Cv)[(size_t)row * N + col] = (__bf16)v;
                else
                    ((float*)Cv)[(size_t)row * N + col] = v;
            }
        }
    }
}

// ---------------------------------------------------------------------------
// fp32 -> bf16 cast (vectorized 4/thread).
// ---------------------------------------------------------------------------
__global__ __launch_bounds__(256) void cast_bf16_kernel(
    const float* __restrict__ src, __bf16* __restrict__ dst, long n)
{
    long i = ((long)blockIdx.x * 256 + threadIdx.x) * 4;
    if (i >= n) return;
    float4 v = *(const float4*)(src + i);
    bf16x4 o = {(__bf16)v.x, (__bf16)v.y, (__bf16)v.z, (__bf16)v.w};
    *(bf16x4*)(dst + i) = o;
}

// ---------------------------------------------------------------------------
// Transpose-cast: src fp32 [R,Cc] -> dst bf16 [Cc,R]. R,Cc multiples of 32.
// ---------------------------------------------------------------------------
__global__ __launch_bounds__(256) void transpose_cast(
    const float* __restrict__ src, __bf16* __restrict__ dst, int R, int Cc)
{
    __shared__ float tile[32][33];
    int c0 = blockIdx.x * 32, r0 = blockIdx.y * 32;
    int tx = threadIdx.x, ty = threadIdx.y;   // 32 x 8
#pragma unroll
    for (int i = 0; i < 32; i += 8)
        tile[ty + i][tx] = src[(size_t)(r0 + ty + i) * Cc + c0 + tx];
    __syncthreads();
#pragma unroll
    for (int i = 0; i < 32; i += 8)
        dst[(size_t)(c0 + ty + i) * R + r0 + tx] = (__bf16)tile[tx][ty + i];
}

// Tiny transpose for conv weights: cw[DINNER,4] -> cwT[4,DINNER].
__global__ __launch_bounds__(256) void conv_w_transpose(
    const float* __restrict__ cw, float* __restrict__ cwT)
{
    int i = blockIdx.x * 256 + threadIdx.x;     // < DCONV*DINNER
    int k = i / DINNER, d = i % DINNER;
    cwT[i] = cw[d * DCONV + k];
}

// ---------------------------------------------------------------------------
// Causal depthwise conv (d_conv=4) + SiLU, bf16 in/out.
// Block = 256 threads covering all DINNER channels (8 ch/thread); each block
// processes CONVT=8 consecutive rows of one sequence with a sliding 4-row
// register window (each xz row read exactly once). Weights via cwT [4,DINNER]
// -> coalesced float4 loads, cached in registers across the row loop.
// ---------------------------------------------------------------------------
__global__ __launch_bounds__(256) void conv_silu_kernel(
    const __bf16* __restrict__ xz16,   // [BL, NXZ], xb half
    const float* __restrict__ cwT,     // [4, DINNER]
    const float* __restrict__ cb,      // [DINNER]
    __bf16* __restrict__ xc16)         // [BL, DINNER]
{
    const int d  = threadIdx.x * 8;
    const long r0 = (long)blockIdx.x * CONVT;
    const int t0 = (int)(r0 & (SEQLEN - 1));

    float wreg[DCONV][8];
#pragma unroll
    for (int k = 0; k < DCONV; ++k) {
        float4 a = *(const float4*)(cwT + k * DINNER + d);
        float4 b = *(const float4*)(cwT + k * DINNER + d + 4);
        wreg[k][0]=a.x; wreg[k][1]=a.y; wreg[k][2]=a.z; wreg[k][3]=a.w;
        wreg[k][4]=b.x; wreg[k][5]=b.y; wreg[k][6]=b.z; wreg[k][7]=b.w;
    }
    float bias[8];
    {
        float4 a = *(const float4*)(cb + d);
        float4 b = *(const float4*)(cb + d + 4);
        bias[0]=a.x; bias[1]=a.y; bias[2]=a.z; bias[3]=a.w;
        bias[4]=b.x; bias[5]=b.y; bias[6]=b.z; bias[7]=b.w;
    }

    const bf16x8 zero = {};
    bf16x8 win[DCONV];   // win[k] = row (t - 3 + k)
#pragma unroll
    for (int j = 0; j < DCONV - 1; ++j) {
        int tt = t0 - (DCONV - 1) + j;
        win[j] = (tt >= 0) ? *(const bf16x8*)(xz16 + (r0 - (DCONV - 1) + j) * NXZ + d)
                           : zero;
    }

    for (int i = 0; i < CONVT; ++i) {
        long r = r0 + i;
        win[DCONV - 1] = *(const bf16x8*)(xz16 + r * NXZ + d);
        bf16x8 o;
#pragma unroll
        for (int j = 0; j < 8; ++j) {
            float acc = bias[j];
#pragma unroll
            for (int k = 0; k < DCONV; ++k)
                acc += (float)win[k][j] * wreg[k][j];
            o[j] = (__bf16)silu_f(acc);
        }
        *(bf16x8*)(xc16 + r * DINNER + d) = o;
#pragma unroll
        for (int k = 0; k < DCONV - 1; ++k)
            win[k] = win[k + 1];
    }
}

// ---------------------------------------------------------------------------
// Split-K GEMM for x_dbl: A[4096,2048] bf16 * W[2048,96] fp32 -> partials.
// ---------------------------------------------------------------------------
__global__ __launch_bounds__(256) void gemm_xdbl_split(
    const __bf16* __restrict__ A,    // [BL, DINNER] bf16
    const float* __restrict__ W,     // [DINNER, 96]
    float* __restrict__ parts)       // [KSPLIT, BL, 96]
{
    __shared__ float As[16][65];
    __shared__ float Bs[16][97];

    const int tid  = threadIdx.x;
    const int row0 = blockIdx.x * 64;
    const int kz   = blockIdx.y;
    const int kbeg = kz * KC;

    const int tr = tid >> 4;
    const int tc = tid & 15;

    const int arow = tid >> 2;
    const int akq  = (tid & 3) * 4;
    const int brow = tid >> 4;
    const int bcol = (tid & 15) * 6;

    float acc[4][6] = {};

    for (int k0 = kbeg; k0 < kbeg + KC; k0 += 16) {
        {
            bf16x4 v = *(const bf16x4*)(A + (size_t)(row0 + arow) * DINNER + k0 + akq);
            As[akq + 0][arow] = (float)v[0];
            As[akq + 1][arow] = (float)v[1];
            As[akq + 2][arow] = (float)v[2];
            As[akq + 3][arow] = (float)v[3];
        }
#pragma unroll
        for (int j = 0; j < 6; ++j)
            Bs[brow][bcol + j] = W[(size_t)(k0 + brow) * XDBL_N + bcol + j];
        __syncthreads();

#pragma unroll
        for (int kk = 0; kk < 16; ++kk) {
            float a[4], b[6];
#pragma unroll
            for (int i = 0; i < 4; ++i) a[i] = As[kk][tr * 4 + i];
#pragma unroll
            for (int j = 0; j < 6; ++j) b[j] = Bs[kk][tc * 6 + j];
#pragma unroll
            for (int i = 0; i < 4; ++i)
#pragma unroll
                for (int j = 0; j < 6; ++j)
                    acc[i][j] += a[i] * b[j];
        }
        __syncthreads();
    }

    const long base = (long)kz * BL * XDBL_N;
#pragma unroll
    for (int i = 0; i < 4; ++i) {
        long off = base + (long)(row0 + tr * 4 + i) * XDBL_N + tc * 6;
#pragma unroll
        for (int j = 0; j < 6; ++j)
            parts[off + j] = acc[i][j];
    }
}

// Reduce KSPLIT partials -> xdbl [BL, 96]; cols<64 also stored bf16 (dt_low).
__global__ __launch_bounds__(256) void xdbl_reduce(
    const float* __restrict__ parts, float* __restrict__ xdbl,
    __bf16* __restrict__ dtlow16)
{
    long i = (long)blockIdx.x * 256 + threadIdx.x;   // < BL*96
    float s = 0.f;
#pragma unroll
    for (int kz = 0; kz < KSPLIT; ++kz)
        s += parts[(long)kz * BL * XDBL_N + i];
    xdbl[i] = s;
    int col = (int)(i % XDBL_N);
    if (col < DTRANK) {
        long row = i / XDBL_N;
        dtlow16[row * DTRANK + col] = (__bf16)s;
    }
}

// ---------------------------------------------------------------------------
// Chunked parallel scan. Summaries in dedicated scratch:
//   sums_h[(bc*16+n)*DINNER + d], sums_p same layout (P, then hstart).
// ---------------------------------------------------------------------------
__global__ __launch_bounds__(256) void scan_pass1(
    const float* __restrict__ dt,
    const __bf16* __restrict__ xc16,
    const float* __restrict__ xdbl,
    const float* __restrict__ A_log,
    float* __restrict__ sums_h,
    float* __restrict__ sums_p)
{
    const int d  = blockIdx.x * 256 + threadIdx.x;
    const int bc = blockIdx.y;
    const int b  = bc / NCHUNK, c = bc % NCHUNK;
    const long r0 = (long)b * SEQLEN + (long)c * LCH;

    float Ad[DSTATE];
    {
        const float4* al = (const float4*)(A_log + d * DSTATE);
#pragma unroll
        for (int q = 0; q < 4; ++q) {
            float4 v = al[q];
            Ad[q * 4 + 0] = -__expf(v.x); Ad[q * 4 + 1] = -__expf(v.y);
            Ad[q * 4 + 2] = -__expf(v.z); Ad[q * 4 + 3] = -__expf(v.w);
        }
    }

    float h[DSTATE] = {};
    float Pp[DSTATE];
#pragma unroll
    for (int n = 0; n < DSTATE; ++n) Pp[n] = 1.f;

    for (int t = 0; t < LCH; ++t) {
        long r = r0 + t;
        float dtv = dt[r * DINNER + d];
        float xv  = (float)xc16[r * DINNER + d];
        float xdt = xv * dtv;
        const float4* bv = (const float4*)(xdbl + r * XDBL_N + DTRANK);
        float4 B0 = bv[0], B1 = bv[1], B2 = bv[2], B3 = bv[3];
        const float Bn[DSTATE] = {B0.x,B0.y,B0.z,B0.w, B1.x,B1.y,B1.z,B1.w,
                                  B2.x,B2.y,B2.z,B2.w, B3.x,B3.y,B3.z,B3.w};
#pragma unroll
        for (int n = 0; n < DSTATE; ++n) {
            float dA = __expf(Ad[n] * dtv);
            h[n] = h[n] * dA + xdt * Bn[n];
            Pp[n] *= dA;
        }
    }

    const long rowbase = (long)bc * DSTATE;
#pragma unroll
    for (int n = 0; n < DSTATE; ++n) {
        sums_h[(rowbase + n) * DINNER + d] = h[n];
        sums_p[(rowbase + n) * DINNER + d] = Pp[n];
    }
}

__global__ __launch_bounds__(256) void scan_combine(
    float* __restrict__ sums_h, float* __restrict__ sums_p)
{
    int u = blockIdx.x * 256 + threadIdx.x;
    int d = u & (DINNER - 1);
    int n = (u >> 11) & (DSTATE - 1);
    int b = u >> 15;
    float hg = 0.f;
    for (int c = 0; c < NCHUNK; ++c) {
        long row = (long)(b * NCHUNK + c) * DSTATE + n;
        float p  = sums_p[row * DINNER + d];
        float hl = sums_h[row * DINNER + d];
        sums_p[row * DINNER + d] = hg;   // hstart for this chunk
        hg = p * hg + hl;
    }
}

// Pass 3: replay from hstart, fused gate, emit bf16 gated activation.
__global__ __launch_bounds__(256) void scan_pass3(
    const float* __restrict__ dt,
    const __bf16* __restrict__ xc16,
    const float* __restrict__ xdbl,
    const float* __restrict__ A_log,
    const __bf16* __restrict__ xz16,  // z half at col DINNER+d
    const float* __restrict__ sums_p, // hstart
    const float* __restrict__ Dp,
    __bf16* __restrict__ gated)       // [BL, DINNER] bf16
{
    const int d  = blockIdx.x * 256 + threadIdx.x;
    const int bc = blockIdx.y;
    const int b  = bc / NCHUNK, c = bc % NCHUNK;
    const long r0 = (long)b * SEQLEN + (long)c * LCH;

    float Ad[DSTATE];
    {
        const float4* al = (const float4*)(A_log + d * DSTATE);
#pragma unroll
        for (int q = 0; q < 4; ++q) {
            float4 v = al[q];
            Ad[q * 4 + 0] = -__expf(v.x); Ad[q * 4 + 1] = -__expf(v.y);
            Ad[q * 4 + 2] = -__expf(v.z); Ad[q * 4 + 3] = -__expf(v.w);
        }
    }

    float h[DSTATE];
    const long rowbase = (long)bc * DSTATE;
#pragma unroll
    for (int n = 0; n < DSTATE; ++n)
        h[n] = sums_p[(rowbase + n) * DINNER + d];

    const float Dv = Dp[d];

    for (int t = 0; t < LCH; ++t) {
        long r = r0 + t;
        float dtv = dt[r * DINNER + d];
        float xv  = (float)xc16[r * DINNER + d];
        float xdt = xv * dtv;
        const float4* bv = (const float4*)(xdbl + r * XDBL_N + DTRANK);
        float4 B0 = bv[0], B1 = bv[1], B2 = bv[2], B3 = bv[3];
        float4 C0 = bv[4], C1 = bv[5], C2 = bv[6], C3 = bv[7];
        const float Bn[DSTATE] = {B0.x,B0.y,B0.z,B0.w, B1.x,B1.y,B1.z,B1.w,
                                  B2.x,B2.y,B2.z,B2.w, B3.x,B3.y,B3.z,B3.w};
        const float Cn[DSTATE] = {C0.x,C0.y,C0.z,C0.w, C1.x,C1.y,C1.z,C1.w,
                                  C2.x,C2.y,C2.z,C2.w, C3.x,C3.y,C3.z,C3.w};
        float y = 0.f;
#pragma unroll
        for (int n = 0; n < DSTATE; ++n) {
            float dA = __expf(Ad[n] * dtv);
            h[n] = h[n] * dA + xdt * Bn[n];
            y += h[n] * Cn[n];
        }
        float z = (float)xz16[r * NXZ + DINNER + d];
        float yy = y + xv * Dv;
        gated[r * DINNER + d] = (__bf16)(yy * silu_f(z));
    }
}

// ---------------------------------------------------------------------------
extern "C" void kernel_launch(void* const* d_in, const int* in_sizes, int n_in,
                              void* d_out, int out_size, void* d_ws, size_t ws_size,
                              hipStream_t stream) {
    const float* x      = (const float*)d_in[0];  // [B,L,DMODEL]
    const float* W_in   = (const float*)d_in[1];  // [DMODEL, NXZ]
    const float* conv_w = (const float*)d_in[2];  // [DINNER, 4]
    const float* conv_b = (const float*)d_in[3];  // [DINNER]
    const float* W_x    = (const float*)d_in[4];  // [DINNER, 96]
    const float* W_dt   = (const float*)d_in[5];  // [DTRANK, DINNER]
    const float* b_dt   = (const float*)d_in[6];  // [DINNER]
    const float* A_log  = (const float*)d_in[7];  // [DINNER, 16]
    const float* Dp     = (const float*)d_in[8];  // [DINNER]
    const float* W_out  = (const float*)d_in[9];  // [DINNER, DMODEL]
    float* out = (float*)d_out;                   // [B,L,DMODEL]

    // Workspace layout (all distinct, ~141 MB total):
    __bf16* xz16    = (__bf16*)d_ws;                    // BL*NXZ       (33.5 MB)
    __bf16* xc16    = xz16 + (long)BL * NXZ;            // BL*DINNER    (16.8 MB)
    float*  xdbl    = (float*)(xc16 + (long)BL * DINNER);   // BL*96    ( 1.6 MB)
    float*  dt      = xdbl + (long)BL * XDBL_N;         // BL*DINNER    (33.5 MB)
    __bf16* gated16 = (__bf16*)(dt + (long)BL * DINNER);    // BL*DINNER(16.8 MB)
    __bf16* WoT16   = gated16 + (long)BL * DINNER;      // DINNER*DMODEL( 4.2 MB)
    __bf16* WdtT16  = WoT16 + (long)DINNER * DMODEL;    // DINNER*64    ( 0.3 MB)
    __bf16* dtlow16 = WdtT16 + (long)DINNER * DTRANK;   // BL*64        ( 0.5 MB)
    __bf16* xb16    = dtlow16 + (long)BL * DTRANK;      // BL*DMODEL    ( 8.4 MB)
    __bf16* WiT16   = xb16 + (long)BL * DMODEL;         // NXZ*DMODEL   ( 8.4 MB)
    float*  cwT     = (float*)(WiT16 + (long)NXZ * DMODEL); // 4*DINNER ( 32 KB)
    float*  scratch = cwT + (long)DCONV * DINNER;       // max(partials 12.6, sums 16.8 MB)
    float*  sums_h  = scratch;                          // 1024*DINNER  ( 8.4 MB)
    float*  sums_p  = scratch + (long)BATCH * NCHUNK * DSTATE * DINNER; // 8.4 MB

    dim3 blk(256);

    // 0) casts: x -> bf16; W_in/W_out/W_dt -> bf16^T; conv_w -> [4,DINNER]
    cast_bf16_kernel<<<dim3((BL * DMODEL / 4) / 256), blk, 0, stream>>>(
        x, xb16, (long)BL * DMODEL);
    transpose_cast<<<dim3(NXZ / 32, DMODEL / 32), dim3(32, 8), 0, stream>>>(
        W_in, WiT16, DMODEL, NXZ);
    transpose_cast<<<dim3(DMODEL / 32, DINNER / 32), dim3(32, 8), 0, stream>>>(
        W_out, WoT16, DINNER, DMODEL);
    transpose_cast<<<dim3(DINNER / 32, DTRANK / 32), dim3(32, 8), 0, stream>>>(
        W_dt, WdtT16, DTRANK, DINNER);
    conv_w_transpose<<<dim3((DCONV * DINNER) / 256), blk, 0, stream>>>(conv_w, cwT);

    // 1) xz = x @ W_in   (MFMA bf16, bf16 store)
    gemm_bt_mfma<2><<<dim3(NXZ / 128, BL / 128), blk, 0, stream>>>(
        xb16, WiT16, xz16, BL, NXZ, DMODEL, nullptr);

    // 2) causal depthwise conv + silu -> xc16 (register window, 8 rows/block)
    conv_silu_kernel<<<dim3(BL / CONVT), blk, 0, stream>>>(
        xz16, cwT, conv_b, xc16);

    // 3) x_dbl = xc @ W_x   (split-K, bf16 A; partials in scratch)
    gemm_xdbl_split<<<dim3(BL / 64, KSPLIT), blk, 0, stream>>>(xc16, W_x, scratch);
    xdbl_reduce<<<dim3((BL * XDBL_N) / 256), blk, 0, stream>>>(scratch, xdbl, dtlow16);

    // 4) dt = softplus(dt_low @ W_dt + b_dt)   (MFMA bf16, fp32 out)
    gemm_bt_mfma<1><<<dim3(DINNER / 128, BL / 128), blk, 0, stream>>>(
        dtlow16, WdtT16, dt, BL, DINNER, DTRANK, b_dt);

    // 5) chunked scan: pass1 -> combine -> pass3 (+fused gate, bf16 out)
    {
        dim3 grid1(DINNER / 256, BATCH * NCHUNK);
        scan_pass1<<<grid1, blk, 0, stream>>>(dt, xc16, xdbl, A_log, sums_h, sums_p);
        scan_combine<<<dim3((BATCH * DSTATE * DINNER) / 256), blk, 0, stream>>>(
            sums_h, sums_p);
        scan_pass3<<<grid1, blk, 0, stream>>>(dt, xc16, xdbl, A_log, xz16,
                                              sums_p, Dp, gated16);
    }
    // 7) out = gated @ W_out   (MFMA bf16, fp32 out)
    gemm_bt_mfma<0><<<dim3(DMODEL / 128, BL / 128), blk, 0, stream>>>(
        gated16, WoT16, out, BL, DMODEL, DINNER, nullptr);

    (void)in_sizes; (void)n_in; (void)out_size; (void)ws_size;
}

// Round 10
// 354.953 us; speedup vs baseline: 1.1735x; 1.0418x over previous
//
#include <hip/hip_runtime.h>
#include <hip/hip_bf16.h>

// Problem constants (MambaBlock): B=2, L=2048, d_model=1024, d_inner=2048,
// d_conv=4, dt_rank=64, d_state=16. All inputs/output float32 (per reference).

#define BATCH   2
#define SEQLEN  2048
#define DMODEL  1024
#define DINNER  2048
#define DCONV   4
#define DTRANK  64
#define DSTATE  16
#define BL      (BATCH * SEQLEN)         // 4096
#define NXZ     (2 * DINNER)             // 4096
#define XDBL_N  (DTRANK + 2 * DSTATE)    // 96
#define LCH     64                       // chunk length for parallel scan
#define NCHUNK  (SEQLEN / LCH)           // 32 chunks per sequence
#define KSPLIT  8                        // split-K for the x_dbl GEMM
#define KC      (DINNER / KSPLIT)        // 256
#define CONVT   8                        // rows per conv block

typedef __bf16 bf16x8 __attribute__((ext_vector_type(8)));
typedef __bf16 bf16x4 __attribute__((ext_vector_type(4)));
typedef float  floatx4 __attribute__((ext_vector_type(4)));

__device__ __forceinline__ float silu_f(float v) {
    return v / (1.f + __expf(-v));
}

// Fast softplus via native v_exp_f32/v_log_f32 (error ~1e-7, << bf16 noise).
__device__ __forceinline__ float softplus_f(float v) {
    return (v > 20.f) ? v : __logf(1.f + __expf(v));
}

__device__ __forceinline__ void gload_lds16(const __bf16* g, __bf16* l) {
    __builtin_amdgcn_global_load_lds(
        (const __attribute__((address_space(1))) void*)g,
        (__attribute__((address_space(3))) void*)l, 16, 0, 0);
}

// ---------------------------------------------------------------------------
// MFMA bf16 GEMM (m97 structure): C[M,N] = A[M,K] * B[K,N].
// A [M,K] bf16 row-major; BT [N,K] bf16 row-major.
// EPI: 0 = fp32 store; 1 = softplus fp32; 2 = bf16 store; 3 = softplus bf16.
// EPI 2/3 use an LDS-restaged coalesced epilogue (8x bf16x8 stores/thread
// instead of 64x 2-B strided stores).
// ---------------------------------------------------------------------------
template <int EPI>
__global__ __launch_bounds__(256) void gemm_bt_mfma(
    const __bf16* __restrict__ A,
    const __bf16* __restrict__ BT,
    void* __restrict__ Cv,
    int M, int N, int K,
    const float* __restrict__ bias)
{
    __shared__ __bf16 smem[8192];      // [0,4096) = Asm, [4096,8192) = Bsm
    __bf16* Asm = smem;
    __bf16* Bsm = smem + 4096;

    const int tid  = threadIdx.x;
    const int w    = tid >> 6;
    const int lane = tid & 63;
    const int lrow = lane & 15;
    const int quad = lane >> 4;
    const int row0 = blockIdx.y * 128;
    const int col0 = blockIdx.x * 128;
    const int wr   = (w >> 1) * 64;
    const int wc   = (w & 1) * 64;

    const int ldr = tid >> 2;
    const int ldk = (tid & 3) * 8;
    const __bf16* gA = A  + (size_t)(row0 + ldr) * K + ldk;
    const __bf16* gB = BT + (size_t)(col0 + ldr) * K + ldk;
    const size_t half = (size_t)64 * K;
    __bf16* lA0 = Asm + w * 512;
    __bf16* lA1 = Asm + 2048 + w * 512;
    __bf16* lB0 = Bsm + w * 512;
    __bf16* lB1 = Bsm + 2048 + w * 512;

    floatx4 acc[4][4];
#pragma unroll
    for (int i = 0; i < 4; ++i)
#pragma unroll
        for (int j = 0; j < 4; ++j)
            acc[i][j] = (floatx4){0.f, 0.f, 0.f, 0.f};

    for (int k0 = 0; k0 < K; k0 += 32) {
        gload_lds16(gA, lA0);
        gload_lds16(gA + half, lA1);
        gload_lds16(gB, lB0);
        gload_lds16(gB + half, lB1);
        gA += 32; gB += 32;
        __syncthreads();

        bf16x8 af[4], bf[4];
#pragma unroll
        for (int t = 0; t < 4; ++t)
            af[t] = *(const bf16x8*)(Asm + (wr + t * 16 + lrow) * 32 + quad * 8);
#pragma unroll
        for (int t = 0; t < 4; ++t)
            bf[t] = *(const bf16x8*)(Bsm + (wc + t * 16 + lrow) * 32 + quad * 8);

#pragma unroll
        for (int ti = 0; ti < 4; ++ti)
#pragma unroll
            for (int tj = 0; tj < 4; ++tj)
                acc[ti][tj] = __builtin_amdgcn_mfma_f32_16x16x32_bf16(
                    af[ti], bf[tj], acc[ti][tj], 0, 0, 0);
        __syncthreads();
    }

    if (EPI == 2 || EPI == 3) {
        // Per-wave private 64x32 LDS restage (two 32-col halves), XOR-swizzled.
        __bf16* cst = smem + w * 2048;
#pragma unroll
        for (int h = 0; h < 2; ++h) {
#pragma unroll
            for (int ti = 0; ti < 4; ++ti) {
#pragma unroll
                for (int tj = 0; tj < 2; ++tj) {
                    float bv = (EPI == 3)
                        ? bias[col0 + wc + (h * 2 + tj) * 16 + lrow] : 0.f;
#pragma unroll
                    for (int r = 0; r < 4; ++r) {
                        int row = ti * 16 + quad * 4 + r;       // 0..63
                        float v = acc[ti][h * 2 + tj][r];
                        if (EPI == 3) v = softplus_f(v + bv);
                        int s = (row >> 2) & 3;
                        int lcol = (tj * 16 + lrow) ^ (s * 8);
                        cst[row * 32 + lcol] = (__bf16)v;
                    }
                }
            }
            int ss = (lane >> 2) & 3;
            __bf16* gdst = (__bf16*)Cv + (size_t)(row0 + wr + lane) * N
                           + col0 + wc + h * 32;
            const __bf16* src = cst + lane * 32;
#pragma unroll
            for (int q = 0; q < 4; ++q)
                *(bf16x8*)(gdst + q * 8) = *(const bf16x8*)(src + ((q ^ ss) * 8));
        }
    } else {
#pragma unroll
        for (int ti = 0; ti < 4; ++ti) {
#pragma unroll
            for (int tj = 0; tj < 4; ++tj) {
                int col = col0 + wc + tj * 16 + lrow;
                float bv = (EPI == 1) ? bias[col] : 0.f;
#pragma unroll
                for (int r = 0; r < 4; ++r) {
                    int row = row0 + wr + ti * 16 + quad * 4 + r;
                    float v = acc[ti][tj][r];
                    if (EPI == 1) v = softplus_f(v + bv);
                    ((float*)Cv)[(size_t)row * N + col] = v;
                }
            }
        }
    }
}

// ---------------------------------------------------------------------------
// Merged preprocessing: x->bf16 cast, 3 transpose-casts, conv-w transpose.
// One launch, block ranges.
// ---------------------------------------------------------------------------
#define NB_CAST  ((BL * DMODEL / 4) / 256)          // 4096
#define NB_WIN   ((NXZ / 32) * (DMODEL / 32))       // 4096
#define NB_WOUT  ((DMODEL / 32) * (DINNER / 32))    // 2048
#define NB_WDT   ((DINNER / 32) * (DTRANK / 32))    // 128
#define NB_CW    ((DCONV * DINNER) / 256)           // 32

__device__ __forceinline__ void transpose_tile(
    const float* __restrict__ src, __bf16* __restrict__ dst, int R, int Cc,
    int bx, int by, int tid, float* tile)
{
    int tx = tid & 31, ty = tid >> 5;   // 32 x 8
    int c0 = bx * 32, r0 = by * 32;
#pragma unroll
    for (int i = 0; i < 32; i += 8)
        tile[(ty + i) * 33 + tx] = src[(size_t)(r0 + ty + i) * Cc + c0 + tx];
    __syncthreads();
#pragma unroll
    for (int i = 0; i < 32; i += 8)
        dst[(size_t)(c0 + ty + i) * R + r0 + tx] = (__bf16)tile[tx * 33 + ty + i];
}

__global__ __launch_bounds__(256) void prep_kernel(
    const float* __restrict__ x,
    const float* __restrict__ W_in,
    const float* __restrict__ W_out,
    const float* __restrict__ W_dt,
    const float* __restrict__ conv_w,
    __bf16* __restrict__ xb16,
    __bf16* __restrict__ WiT16,
    __bf16* __restrict__ WoT16,
    __bf16* __restrict__ WdtT16,
    float* __restrict__ cwT)
{
    __shared__ float tile[32 * 33];
    const int tid = threadIdx.x;
    int bid = blockIdx.x;

    if (bid < NB_CAST) {
        long i = ((long)bid * 256 + tid) * 4;
        float4 v = *(const float4*)(x + i);
        bf16x4 o = {(__bf16)v.x, (__bf16)v.y, (__bf16)v.z, (__bf16)v.w};
        *(bf16x4*)(xb16 + i) = o;
        return;
    }
    bid -= NB_CAST;
    if (bid < NB_WIN) {
        transpose_tile(W_in, WiT16, DMODEL, NXZ,
                       bid % (NXZ / 32), bid / (NXZ / 32), tid, tile);
        return;
    }
    bid -= NB_WIN;
    if (bid < NB_WOUT) {
        transpose_tile(W_out, WoT16, DINNER, DMODEL,
                       bid % (DMODEL / 32), bid / (DMODEL / 32), tid, tile);
        return;
    }
    bid -= NB_WOUT;
    if (bid < NB_WDT) {
        transpose_tile(W_dt, WdtT16, DTRANK, DINNER,
                       bid % (DINNER / 32), bid / (DINNER / 32), tid, tile);
        return;
    }
    bid -= NB_WDT;
    {
        int i = bid * 256 + tid;                  // < DCONV*DINNER
        int k = i / DINNER, d = i % DINNER;
        cwT[i] = conv_w[d * DCONV + k];
    }
}

// ---------------------------------------------------------------------------
// Causal depthwise conv (d_conv=4) + SiLU, bf16 in/out, register window.
// ---------------------------------------------------------------------------
__global__ __launch_bounds__(256) void conv_silu_kernel(
    const __bf16* __restrict__ xz16,   // [BL, NXZ], xb half
    const float* __restrict__ cwT,     // [4, DINNER]
    const float* __restrict__ cb,      // [DINNER]
    __bf16* __restrict__ xc16)         // [BL, DINNER]
{
    const int d  = threadIdx.x * 8;
    const long r0 = (long)blockIdx.x * CONVT;
    const int t0 = (int)(r0 & (SEQLEN - 1));

    float wreg[DCONV][8];
#pragma unroll
    for (int k = 0; k < DCONV; ++k) {
        float4 a = *(const float4*)(cwT + k * DINNER + d);
        float4 b = *(const float4*)(cwT + k * DINNER + d + 4);
        wreg[k][0]=a.x; wreg[k][1]=a.y; wreg[k][2]=a.z; wreg[k][3]=a.w;
        wreg[k][4]=b.x; wreg[k][5]=b.y; wreg[k][6]=b.z; wreg[k][7]=b.w;
    }
    float bias[8];
    {
        float4 a = *(const float4*)(cb + d);
        float4 b = *(const float4*)(cb + d + 4);
        bias[0]=a.x; bias[1]=a.y; bias[2]=a.z; bias[3]=a.w;
        bias[4]=b.x; bias[5]=b.y; bias[6]=b.z; bias[7]=b.w;
    }

    const bf16x8 zero = {};
    bf16x8 win[DCONV];   // win[k] = row (t - 3 + k)
#pragma unroll
    for (int j = 0; j < DCONV - 1; ++j) {
        int tt = t0 - (DCONV - 1) + j;
        win[j] = (tt >= 0) ? *(const bf16x8*)(xz16 + (r0 - (DCONV - 1) + j) * NXZ + d)
                           : zero;
    }

    for (int i = 0; i < CONVT; ++i) {
        long r = r0 + i;
        win[DCONV - 1] = *(const bf16x8*)(xz16 + r * NXZ + d);
        bf16x8 o;
#pragma unroll
        for (int j = 0; j < 8; ++j) {
            float acc = bias[j];
#pragma unroll
            for (int k = 0; k < DCONV; ++k)
                acc += (float)win[k][j] * wreg[k][j];
            o[j] = (__bf16)silu_f(acc);
        }
        *(bf16x8*)(xc16 + r * DINNER + d) = o;
#pragma unroll
        for (int k = 0; k < DCONV - 1; ++k)
            win[k] = win[k + 1];
    }
}

// ---------------------------------------------------------------------------
// Split-K GEMM for x_dbl: A[4096,2048] bf16 * W[2048,96] fp32 -> partials.
// ---------------------------------------------------------------------------
__global__ __launch_bounds__(256) void gemm_xdbl_split(
    const __bf16* __restrict__ A,
    const float* __restrict__ W,
    float* __restrict__ parts)       // [KSPLIT, BL, 96]
{
    __shared__ float As[16][65];
    __shared__ float Bs[16][97];

    const int tid  = threadIdx.x;
    const int row0 = blockIdx.x * 64;
    const int kz   = blockIdx.y;
    const int kbeg = kz * KC;

    const int tr = tid >> 4;
    const int tc = tid & 15;

    const int arow = tid >> 2;
    const int akq  = (tid & 3) * 4;
    const int brow = tid >> 4;
    const int bcol = (tid & 15) * 6;

    float acc[4][6] = {};

    for (int k0 = kbeg; k0 < kbeg + KC; k0 += 16) {
        {
            bf16x4 v = *(const bf16x4*)(A + (size_t)(row0 + arow) * DINNER + k0 + akq);
            As[akq + 0][arow] = (float)v[0];
            As[akq + 1][arow] = (float)v[1];
            As[akq + 2][arow] = (float)v[2];
            As[akq + 3][arow] = (float)v[3];
        }
#pragma unroll
        for (int j = 0; j < 6; ++j)
            Bs[brow][bcol + j] = W[(size_t)(k0 + brow) * XDBL_N + bcol + j];
        __syncthreads();

#pragma unroll
        for (int kk = 0; kk < 16; ++kk) {
            float a[4], b[6];
#pragma unroll
            for (int i = 0; i < 4; ++i) a[i] = As[kk][tr * 4 + i];
#pragma unroll
            for (int j = 0; j < 6; ++j) b[j] = Bs[kk][tc * 6 + j];
#pragma unroll
            for (int i = 0; i < 4; ++i)
#pragma unroll
                for (int j = 0; j < 6; ++j)
                    acc[i][j] += a[i] * b[j];
        }
        __syncthreads();
    }

    const long base = (long)kz * BL * XDBL_N;
#pragma unroll
    for (int i = 0; i < 4; ++i) {
        long off = base + (long)(row0 + tr * 4 + i) * XDBL_N + tc * 6;
#pragma unroll
        for (int j = 0; j < 6; ++j)
            parts[off + j] = acc[i][j];
    }
}

// Reduce KSPLIT partials -> xdbl [BL, 96]; cols<64 also stored bf16 (dt_low).
__global__ __launch_bounds__(256) void xdbl_reduce(
    const float* __restrict__ parts, float* __restrict__ xdbl,
    __bf16* __restrict__ dtlow16)
{
    long i = (long)blockIdx.x * 256 + threadIdx.x;   // < BL*96
    float s = 0.f;
#pragma unroll
    for (int kz = 0; kz < KSPLIT; ++kz)
        s += parts[(long)kz * BL * XDBL_N + i];
    xdbl[i] = s;
    int col = (int)(i % XDBL_N);
    if (col < DTRANK) {
        long row = i / XDBL_N;
        dtlow16[row * DTRANK + col] = (__bf16)s;
    }
}

// ---------------------------------------------------------------------------
// Chunked parallel scan (dt now bf16).
// ---------------------------------------------------------------------------
__global__ __launch_bounds__(256) void scan_pass1(
    const __bf16* __restrict__ dt16,
    const __bf16* __restrict__ xc16,
    const float* __restrict__ xdbl,
    const float* __restrict__ A_log,
    float* __restrict__ sums_h,
    float* __restrict__ sums_p)
{
    const int d  = blockIdx.x * 256 + threadIdx.x;
    const int bc = blockIdx.y;
    const int b  = bc / NCHUNK, c = bc % NCHUNK;
    const long r0 = (long)b * SEQLEN + (long)c * LCH;

    float Ad[DSTATE];
    {
        const float4* al = (const float4*)(A_log + d * DSTATE);
#pragma unroll
        for (int q = 0; q < 4; ++q) {
            float4 v = al[q];
            Ad[q * 4 + 0] = -__expf(v.x); Ad[q * 4 + 1] = -__expf(v.y);
            Ad[q * 4 + 2] = -__expf(v.z); Ad[q * 4 + 3] = -__expf(v.w);
        }
    }

    float h[DSTATE] = {};
    float Pp[DSTATE];
#pragma unroll
    for (int n = 0; n < DSTATE; ++n) Pp[n] = 1.f;

    for (int t = 0; t < LCH; ++t) {
        long r = r0 + t;
        float dtv = (float)dt16[r * DINNER + d];
        float xv  = (float)xc16[r * DINNER + d];
        float xdt = xv * dtv;
        const float4* bv = (const float4*)(xdbl + r * XDBL_N + DTRANK);
        float4 B0 = bv[0], B1 = bv[1], B2 = bv[2], B3 = bv[3];
        const float Bn[DSTATE] = {B0.x,B0.y,B0.z,B0.w, B1.x,B1.y,B1.z,B1.w,
                                  B2.x,B2.y,B2.z,B2.w, B3.x,B3.y,B3.z,B3.w};
#pragma unroll
        for (int n = 0; n < DSTATE; ++n) {
            float dA = __expf(Ad[n] * dtv);
            h[n] = h[n] * dA + xdt * Bn[n];
            Pp[n] *= dA;
        }
    }

    const long rowbase = (long)bc * DSTATE;
#pragma unroll
    for (int n = 0; n < DSTATE; ++n) {
        sums_h[(rowbase + n) * DINNER + d] = h[n];
        sums_p[(rowbase + n) * DINNER + d] = Pp[n];
    }
}

__global__ __launch_bounds__(256) void scan_combine(
    float* __restrict__ sums_h, float* __restrict__ sums_p)
{
    int u = blockIdx.x * 256 + threadIdx.x;
    int d = u & (DINNER - 1);
    int n = (u >> 11) & (DSTATE - 1);
    int b = u >> 15;
    float hg = 0.f;
    for (int c = 0; c < NCHUNK; ++c) {
        long row = (long)(b * NCHUNK + c) * DSTATE + n;
        float p  = sums_p[row * DINNER + d];
        float hl = sums_h[row * DINNER + d];
        sums_p[row * DINNER + d] = hg;   // hstart for this chunk
        hg = p * hg + hl;
    }
}

// Pass 3: replay from hstart, fused gate, emit bf16 gated activation.
__global__ __launch_bounds__(256) void scan_pass3(
    const __bf16* __restrict__ dt16,
    const __bf16* __restrict__ xc16,
    const float* __restrict__ xdbl,
    const float* __restrict__ A_log,
    const __bf16* __restrict__ xz16,  // z half at col DINNER+d
    const float* __restrict__ sums_p, // hstart
    const float* __restrict__ Dp,
    __bf16* __restrict__ gated)       // [BL, DINNER] bf16
{
    const int d  = blockIdx.x * 256 + threadIdx.x;
    const int bc = blockIdx.y;
    const int b  = bc / NCHUNK, c = bc % NCHUNK;
    const long r0 = (long)b * SEQLEN + (long)c * LCH;

    float Ad[DSTATE];
    {
        const float4* al = (const float4*)(A_log + d * DSTATE);
#pragma unroll
        for (int q = 0; q < 4; ++q) {
            float4 v = al[q];
            Ad[q * 4 + 0] = -__expf(v.x); Ad[q * 4 + 1] = -__expf(v.y);
            Ad[q * 4 + 2] = -__expf(v.z); Ad[q * 4 + 3] = -__expf(v.w);
        }
    }

    float h[DSTATE];
    const long rowbase = (long)bc * DSTATE;
#pragma unroll
    for (int n = 0; n < DSTATE; ++n)
        h[n] = sums_p[(rowbase + n) * DINNER + d];

    const float Dv = Dp[d];

    for (int t = 0; t < LCH; ++t) {
        long r = r0 + t;
        float dtv = (float)dt16[r * DINNER + d];
        float xv  = (float)xc16[r * DINNER + d];
        float xdt = xv * dtv;
        const float4* bv = (const float4*)(xdbl + r * XDBL_N + DTRANK);
        float4 B0 = bv[0], B1 = bv[1], B2 = bv[2], B3 = bv[3];
        float4 C0 = bv[4], C1 = bv[5], C2 = bv[6], C3 = bv[7];
        const float Bn[DSTATE] = {B0.x,B0.y,B0.z,B0.w, B1.x,B1.y,B1.z,B1.w,
                                  B2.x,B2.y,B2.z,B2.w, B3.x,B3.y,B3.z,B3.w};
        const float Cn[DSTATE] = {C0.x,C0.y,C0.z,C0.w, C1.x,C1.y,C1.z,C1.w,
                                  C2.x,C2.y,C2.z,C2.w, C3.x,C3.y,C3.z,C3.w};
        float y = 0.f;
#pragma unroll
        for (int n = 0; n < DSTATE; ++n) {
            float dA = __expf(Ad[n] * dtv);
            h[n] = h[n] * dA + xdt * Bn[n];
            y += h[n] * Cn[n];
        }
        float z = (float)xz16[r * NXZ + DINNER + d];
        float yy = y + xv * Dv;
        gated[r * DINNER + d] = (__bf16)(yy * silu_f(z));
    }
}

// ---------------------------------------------------------------------------
extern "C" void kernel_launch(void* const* d_in, const int* in_sizes, int n_in,
                              void* d_out, int out_size, void* d_ws, size_t ws_size,
                              hipStream_t stream) {
    const float* x      = (const float*)d_in[0];
    const float* W_in   = (const float*)d_in[1];
    const float* conv_w = (const float*)d_in[2];
    const float* conv_b = (const float*)d_in[3];
    const float* W_x    = (const float*)d_in[4];
    const float* W_dt   = (const float*)d_in[5];
    const float* b_dt   = (const float*)d_in[6];
    const float* A_log  = (const float*)d_in[7];
    const float* Dp     = (const float*)d_in[8];
    const float* W_out  = (const float*)d_in[9];
    float* out = (float*)d_out;

    // Workspace layout (~124 MB):
    __bf16* xz16    = (__bf16*)d_ws;                    // BL*NXZ
    __bf16* xc16    = xz16 + (long)BL * NXZ;            // BL*DINNER
    __bf16* dt16    = xc16 + (long)BL * DINNER;         // BL*DINNER
    __bf16* gated16 = dt16 + (long)BL * DINNER;         // BL*DINNER
    __bf16* WoT16   = gated16 + (long)BL * DINNER;      // DINNER*DMODEL
    __bf16* WdtT16  = WoT16 + (long)DINNER * DMODEL;    // DINNER*DTRANK
    __bf16* dtlow16 = WdtT16 + (long)DINNER * DTRANK;   // BL*DTRANK
    __bf16* xb16    = dtlow16 + (long)BL * DTRANK;      // BL*DMODEL
    __bf16* WiT16   = xb16 + (long)BL * DMODEL;         // NXZ*DMODEL
    float*  xdbl    = (float*)(WiT16 + (long)NXZ * DMODEL);  // BL*96
    float*  cwT     = xdbl + (long)BL * XDBL_N;         // 4*DINNER
    float*  scratch = cwT + (long)DCONV * DINNER;       // partials / sums
    float*  sums_h  = scratch;                          // 1024*DINNER
    float*  sums_p  = scratch + (long)BATCH * NCHUNK * DSTATE * DINNER;

    dim3 blk(256);

    // 0) merged prep: cast + 3 weight transposes + conv-w transpose
    prep_kernel<<<dim3(NB_CAST + NB_WIN + NB_WOUT + NB_WDT + NB_CW), blk, 0, stream>>>(
        x, W_in, W_out, W_dt, conv_w, xb16, WiT16, WoT16, WdtT16, cwT);

    // 1) xz = x @ W_in   (MFMA bf16, LDS-staged bf16 store)
    gemm_bt_mfma<2><<<dim3(NXZ / 128, BL / 128), blk, 0, stream>>>(
        xb16, WiT16, xz16, BL, NXZ, DMODEL, nullptr);

    // 2) causal depthwise conv + silu -> xc16
    conv_silu_kernel<<<dim3(BL / CONVT), blk, 0, stream>>>(
        xz16, cwT, conv_b, xc16);

    // 3) x_dbl = xc @ W_x   (split-K; partials in scratch)
    gemm_xdbl_split<<<dim3(BL / 64, KSPLIT), blk, 0, stream>>>(xc16, W_x, scratch);
    xdbl_reduce<<<dim3((BL * XDBL_N) / 256), blk, 0, stream>>>(scratch, xdbl, dtlow16);

    // 4) dt = softplus(dt_low @ W_dt + b_dt)   (MFMA bf16, bf16 store)
    gemm_bt_mfma<3><<<dim3(DINNER / 128, BL / 128), blk, 0, stream>>>(
        dtlow16, WdtT16, dt16, BL, DINNER, DTRANK, b_dt);

    // 5) chunked scan: pass1 -> combine -> pass3 (+fused gate)
    {
        dim3 grid1(DINNER / 256, BATCH * NCHUNK);
        scan_pass1<<<grid1, blk, 0, stream>>>(dt16, xc16, xdbl, A_log, sums_h, sums_p);
        scan_combine<<<dim3((BATCH * DSTATE * DINNER) / 256), blk, 0, stream>>>(
            sums_h, sums_p);
        scan_pass3<<<grid1, blk, 0, stream>>>(dt16, xc16, xdbl, A_log, xz16,
                                              sums_p, Dp, gated16);
    }
    // 7) out = gated @ W_out   (MFMA bf16, fp32 out)
    gemm_bt_mfma<0><<<dim3(DMODEL / 128, BL / 128), blk, 0, stream>>>(
        gated16, WoT16, out, BL, DMODEL, DINNER, nullptr);

    (void)in_sizes; (void)n_in; (void)out_size; (void)ws_size;
}

// Round 11
// 350.024 us; speedup vs baseline: 1.1901x; 1.0141x over previous
//
#include <hip/hip_runtime.h>
#include <hip/hip_bf16.h>

// Problem constants (MambaBlock): B=2, L=2048, d_model=1024, d_inner=2048,
// d_conv=4, dt_rank=64, d_state=16. All inputs/output float32 (per reference).

#define BATCH   2
#define SEQLEN  2048
#define DMODEL  1024
#define DINNER  2048
#define DCONV   4
#define DTRANK  64
#define DSTATE  16
#define BL      (BATCH * SEQLEN)         // 4096
#define NXZ     (2 * DINNER)             // 4096
#define XDBL_N  (DTRANK + 2 * DSTATE)    // 96
#define LCH     64                       // chunk length for parallel scan
#define NCHUNK  (SEQLEN / LCH)           // 32 chunks per sequence
#define KSPLIT  8                        // split-K for the x_dbl GEMM
#define KC      (DINNER / KSPLIT)        // 256
#define CONVT   8                        // rows per conv block

typedef __bf16 bf16x8 __attribute__((ext_vector_type(8)));
typedef __bf16 bf16x4 __attribute__((ext_vector_type(4)));
typedef float  floatx4 __attribute__((ext_vector_type(4)));

__device__ __forceinline__ float silu_f(float v) {
    return v / (1.f + __expf(-v));
}

// Fast softplus via native v_exp_f32/v_log_f32 (error ~1e-7, << bf16 noise).
__device__ __forceinline__ float softplus_f(float v) {
    return (v > 20.f) ? v : __logf(1.f + __expf(v));
}

__device__ __forceinline__ void gload_lds16(const __bf16* g, __bf16* l) {
    __builtin_amdgcn_global_load_lds(
        (const __attribute__((address_space(1))) void*)g,
        (__attribute__((address_space(3))) void*)l, 16, 0, 0);
}

// ---------------------------------------------------------------------------
// MFMA bf16 GEMM (m97 structure): C[M,N] = A[M,K] * B[K,N].
// A [M,K] bf16 row-major; BT [N,K] bf16 row-major.
// EPI: 0 = fp32 store; 1 = softplus fp32; 2 = bf16 store; 3 = softplus bf16.
// All epilogues store directly (R10's LDS restage regressed: quad rows alias
// to the same 8 LDS banks -> ~8-way conflicts; direct 2-B stores were never
// the limiter).
// ---------------------------------------------------------------------------
template <int EPI>
__global__ __launch_bounds__(256) void gemm_bt_mfma(
    const __bf16* __restrict__ A,
    const __bf16* __restrict__ BT,
    void* __restrict__ Cv,
    int M, int N, int K,
    const float* __restrict__ bias)
{
    __shared__ __bf16 Asm[128 * 32];
    __shared__ __bf16 Bsm[128 * 32];

    const int tid  = threadIdx.x;
    const int w    = tid >> 6;
    const int lane = tid & 63;
    const int lrow = lane & 15;
    const int quad = lane >> 4;
    const int row0 = blockIdx.y * 128;
    const int col0 = blockIdx.x * 128;
    const int wr   = (w >> 1) * 64;
    const int wc   = (w & 1) * 64;

    const int ldr = tid >> 2;
    const int ldk = (tid & 3) * 8;
    const __bf16* gA = A  + (size_t)(row0 + ldr) * K + ldk;
    const __bf16* gB = BT + (size_t)(col0 + ldr) * K + ldk;
    const size_t half = (size_t)64 * K;
    __bf16* lA0 = Asm + w * 512;
    __bf16* lA1 = Asm + 2048 + w * 512;
    __bf16* lB0 = Bsm + w * 512;
    __bf16* lB1 = Bsm + 2048 + w * 512;

    floatx4 acc[4][4];
#pragma unroll
    for (int i = 0; i < 4; ++i)
#pragma unroll
        for (int j = 0; j < 4; ++j)
            acc[i][j] = (floatx4){0.f, 0.f, 0.f, 0.f};

    for (int k0 = 0; k0 < K; k0 += 32) {
        gload_lds16(gA, lA0);
        gload_lds16(gA + half, lA1);
        gload_lds16(gB, lB0);
        gload_lds16(gB + half, lB1);
        gA += 32; gB += 32;
        __syncthreads();

        bf16x8 af[4], bf[4];
#pragma unroll
        for (int t = 0; t < 4; ++t)
            af[t] = *(const bf16x8*)(Asm + (wr + t * 16 + lrow) * 32 + quad * 8);
#pragma unroll
        for (int t = 0; t < 4; ++t)
            bf[t] = *(const bf16x8*)(Bsm + (wc + t * 16 + lrow) * 32 + quad * 8);

#pragma unroll
        for (int ti = 0; ti < 4; ++ti)
#pragma unroll
            for (int tj = 0; tj < 4; ++tj)
                acc[ti][tj] = __builtin_amdgcn_mfma_f32_16x16x32_bf16(
                    af[ti], bf[tj], acc[ti][tj], 0, 0, 0);
        __syncthreads();
    }

#pragma unroll
    for (int ti = 0; ti < 4; ++ti) {
#pragma unroll
        for (int tj = 0; tj < 4; ++tj) {
            int col = col0 + wc + tj * 16 + lrow;
            float bv = (EPI == 1 || EPI == 3) ? bias[col] : 0.f;
#pragma unroll
            for (int r = 0; r < 4; ++r) {
                int row = row0 + wr + ti * 16 + quad * 4 + r;
                float v = acc[ti][tj][r];
                if (EPI == 1 || EPI == 3) v = softplus_f(v + bv);
                if (EPI == 2 || EPI == 3)
                    ((__bf16*)Cv)[(size_t)row * N + col] = (__bf16)v;
                else
                    ((float*)Cv)[(size_t)row * N + col] = v;
            }
        }
    }
}

// ---------------------------------------------------------------------------
// Merged preprocessing: x->bf16 cast, 3 transpose-casts, conv-w transpose.
// ---------------------------------------------------------------------------
#define NB_CAST  ((BL * DMODEL / 4) / 256)          // 4096
#define NB_WIN   ((NXZ / 32) * (DMODEL / 32))       // 4096
#define NB_WOUT  ((DMODEL / 32) * (DINNER / 32))    // 2048
#define NB_WDT   ((DINNER / 32) * (DTRANK / 32))    // 128
#define NB_CW    ((DCONV * DINNER) / 256)           // 32

__device__ __forceinline__ void transpose_tile(
    const float* __restrict__ src, __bf16* __restrict__ dst, int R, int Cc,
    int bx, int by, int tid, float* tile)
{
    int tx = tid & 31, ty = tid >> 5;   // 32 x 8
    int c0 = bx * 32, r0 = by * 32;
#pragma unroll
    for (int i = 0; i < 32; i += 8)
        tile[(ty + i) * 33 + tx] = src[(size_t)(r0 + ty + i) * Cc + c0 + tx];
    __syncthreads();
#pragma unroll
    for (int i = 0; i < 32; i += 8)
        dst[(size_t)(c0 + ty + i) * R + r0 + tx] = (__bf16)tile[tx * 33 + ty + i];
}

__global__ __launch_bounds__(256) void prep_kernel(
    const float* __restrict__ x,
    const float* __restrict__ W_in,
    const float* __restrict__ W_out,
    const float* __restrict__ W_dt,
    const float* __restrict__ conv_w,
    __bf16* __restrict__ xb16,
    __bf16* __restrict__ WiT16,
    __bf16* __restrict__ WoT16,
    __bf16* __restrict__ WdtT16,
    float* __restrict__ cwT)
{
    __shared__ float tile[32 * 33];
    const int tid = threadIdx.x;
    int bid = blockIdx.x;

    if (bid < NB_CAST) {
        long i = ((long)bid * 256 + tid) * 4;
        float4 v = *(const float4*)(x + i);
        bf16x4 o = {(__bf16)v.x, (__bf16)v.y, (__bf16)v.z, (__bf16)v.w};
        *(bf16x4*)(xb16 + i) = o;
        return;
    }
    bid -= NB_CAST;
    if (bid < NB_WIN) {
        transpose_tile(W_in, WiT16, DMODEL, NXZ,
                       bid % (NXZ / 32), bid / (NXZ / 32), tid, tile);
        return;
    }
    bid -= NB_WIN;
    if (bid < NB_WOUT) {
        transpose_tile(W_out, WoT16, DINNER, DMODEL,
                       bid % (DMODEL / 32), bid / (DMODEL / 32), tid, tile);
        return;
    }
    bid -= NB_WOUT;
    if (bid < NB_WDT) {
        transpose_tile(W_dt, WdtT16, DTRANK, DINNER,
                       bid % (DINNER / 32), bid / (DINNER / 32), tid, tile);
        return;
    }
    bid -= NB_WDT;
    {
        int i = bid * 256 + tid;                  // < DCONV*DINNER
        int k = i / DINNER, d = i % DINNER;
        cwT[i] = conv_w[d * DCONV + k];
    }
}

// ---------------------------------------------------------------------------
// Causal depthwise conv (d_conv=4) + SiLU, bf16 in/out, register window.
// ---------------------------------------------------------------------------
__global__ __launch_bounds__(256) void conv_silu_kernel(
    const __bf16* __restrict__ xz16,   // [BL, NXZ], xb half
    const float* __restrict__ cwT,     // [4, DINNER]
    const float* __restrict__ cb,      // [DINNER]
    __bf16* __restrict__ xc16)         // [BL, DINNER]
{
    const int d  = threadIdx.x * 8;
    const long r0 = (long)blockIdx.x * CONVT;
    const int t0 = (int)(r0 & (SEQLEN - 1));

    float wreg[DCONV][8];
#pragma unroll
    for (int k = 0; k < DCONV; ++k) {
        float4 a = *(const float4*)(cwT + k * DINNER + d);
        float4 b = *(const float4*)(cwT + k * DINNER + d + 4);
        wreg[k][0]=a.x; wreg[k][1]=a.y; wreg[k][2]=a.z; wreg[k][3]=a.w;
        wreg[k][4]=b.x; wreg[k][5]=b.y; wreg[k][6]=b.z; wreg[k][7]=b.w;
    }
    float bias[8];
    {
        float4 a = *(const float4*)(cb + d);
        float4 b = *(const float4*)(cb + d + 4);
        bias[0]=a.x; bias[1]=a.y; bias[2]=a.z; bias[3]=a.w;
        bias[4]=b.x; bias[5]=b.y; bias[6]=b.z; bias[7]=b.w;
    }

    const bf16x8 zero = {};
    bf16x8 win[DCONV];   // win[k] = row (t - 3 + k)
#pragma unroll
    for (int j = 0; j < DCONV - 1; ++j) {
        int tt = t0 - (DCONV - 1) + j;
        win[j] = (tt >= 0) ? *(const bf16x8*)(xz16 + (r0 - (DCONV - 1) + j) * NXZ + d)
                           : zero;
    }

    for (int i = 0; i < CONVT; ++i) {
        long r = r0 + i;
        win[DCONV - 1] = *(const bf16x8*)(xz16 + r * NXZ + d);
        bf16x8 o;
#pragma unroll
        for (int j = 0; j < 8; ++j) {
            float acc = bias[j];
#pragma unroll
            for (int k = 0; k < DCONV; ++k)
                acc += (float)win[k][j] * wreg[k][j];
            o[j] = (__bf16)silu_f(acc);
        }
        *(bf16x8*)(xc16 + r * DINNER + d) = o;
#pragma unroll
        for (int k = 0; k < DCONV - 1; ++k)
            win[k] = win[k + 1];
    }
}

// ---------------------------------------------------------------------------
// Split-K GEMM for x_dbl: A[4096,2048] bf16 * W[2048,96] fp32 -> partials.
// ---------------------------------------------------------------------------
__global__ __launch_bounds__(256) void gemm_xdbl_split(
    const __bf16* __restrict__ A,
    const float* __restrict__ W,
    float* __restrict__ parts)       // [KSPLIT, BL, 96]
{
    __shared__ float As[16][65];
    __shared__ float Bs[16][97];

    const int tid  = threadIdx.x;
    const int row0 = blockIdx.x * 64;
    const int kz   = blockIdx.y;
    const int kbeg = kz * KC;

    const int tr = tid >> 4;
    const int tc = tid & 15;

    const int arow = tid >> 2;
    const int akq  = (tid & 3) * 4;
    const int brow = tid >> 4;
    const int bcol = (tid & 15) * 6;

    float acc[4][6] = {};

    for (int k0 = kbeg; k0 < kbeg + KC; k0 += 16) {
        {
            bf16x4 v = *(const bf16x4*)(A + (size_t)(row0 + arow) * DINNER + k0 + akq);
            As[akq + 0][arow] = (float)v[0];
            As[akq + 1][arow] = (float)v[1];
            As[akq + 2][arow] = (float)v[2];
            As[akq + 3][arow] = (float)v[3];
        }
#pragma unroll
        for (int j = 0; j < 6; ++j)
            Bs[brow][bcol + j] = W[(size_t)(k0 + brow) * XDBL_N + bcol + j];
        __syncthreads();

#pragma unroll
        for (int kk = 0; kk < 16; ++kk) {
            float a[4], b[6];
#pragma unroll
            for (int i = 0; i < 4; ++i) a[i] = As[kk][tr * 4 + i];
#pragma unroll
            for (int j = 0; j < 6; ++j) b[j] = Bs[kk][tc * 6 + j];
#pragma unroll
            for (int i = 0; i < 4; ++i)
#pragma unroll
                for (int j = 0; j < 6; ++j)
                    acc[i][j] += a[i] * b[j];
        }
        __syncthreads();
    }

    const long base = (long)kz * BL * XDBL_N;
#pragma unroll
    for (int i = 0; i < 4; ++i) {
        long off = base + (long)(row0 + tr * 4 + i) * XDBL_N + tc * 6;
#pragma unroll
        for (int j = 0; j < 6; ++j)
            parts[off + j] = acc[i][j];
    }
}

// Reduce KSPLIT partials -> xdbl [BL, 96]; cols<64 also stored bf16 (dt_low).
__global__ __launch_bounds__(256) void xdbl_reduce(
    const float* __restrict__ parts, float* __restrict__ xdbl,
    __bf16* __restrict__ dtlow16)
{
    long i = (long)blockIdx.x * 256 + threadIdx.x;   // < BL*96
    float s = 0.f;
#pragma unroll
    for (int kz = 0; kz < KSPLIT; ++kz)
        s += parts[(long)kz * BL * XDBL_N + i];
    xdbl[i] = s;
    int col = (int)(i % XDBL_N);
    if (col < DTRANK) {
        long row = i / XDBL_N;
        dtlow16[row * DTRANK + col] = (__bf16)s;
    }
}

// ---------------------------------------------------------------------------
// Chunked parallel scan (dt bf16).
// ---------------------------------------------------------------------------
__global__ __launch_bounds__(256) void scan_pass1(
    const __bf16* __restrict__ dt16,
    const __bf16* __restrict__ xc16,
    const float* __restrict__ xdbl,
    const float* __restrict__ A_log,
    float* __restrict__ sums_h,
    float* __restrict__ sums_p)
{
    const int d  = blockIdx.x * 256 + threadIdx.x;
    const int bc = blockIdx.y;
    const int b  = bc / NCHUNK, c = bc % NCHUNK;
    const long r0 = (long)b * SEQLEN + (long)c * LCH;

    float Ad[DSTATE];
    {
        const float4* al = (const float4*)(A_log + d * DSTATE);
#pragma unroll
        for (int q = 0; q < 4; ++q) {
            float4 v = al[q];
            Ad[q * 4 + 0] = -__expf(v.x); Ad[q * 4 + 1] = -__expf(v.y);
            Ad[q * 4 + 2] = -__expf(v.z); Ad[q * 4 + 3] = -__expf(v.w);
        }
    }

    float h[DSTATE] = {};
    float Pp[DSTATE];
#pragma unroll
    for (int n = 0; n < DSTATE; ++n) Pp[n] = 1.f;

    for (int t = 0; t < LCH; ++t) {
        long r = r0 + t;
        float dtv = (float)dt16[r * DINNER + d];
        float xv  = (float)xc16[r * DINNER + d];
        float xdt = xv * dtv;
        const float4* bv = (const float4*)(xdbl + r * XDBL_N + DTRANK);
        float4 B0 = bv[0], B1 = bv[1], B2 = bv[2], B3 = bv[3];
        const float Bn[DSTATE] = {B0.x,B0.y,B0.z,B0.w, B1.x,B1.y,B1.z,B1.w,
                                  B2.x,B2.y,B2.z,B2.w, B3.x,B3.y,B3.z,B3.w};
#pragma unroll
        for (int n = 0; n < DSTATE; ++n) {
            float dA = __expf(Ad[n] * dtv);
            h[n] = h[n] * dA + xdt * Bn[n];
            Pp[n] *= dA;
        }
    }

    const long rowbase = (long)bc * DSTATE;
#pragma unroll
    for (int n = 0; n < DSTATE; ++n) {
        sums_h[(rowbase + n) * DINNER + d] = h[n];
        sums_p[(rowbase + n) * DINNER + d] = Pp[n];
    }
}

__global__ __launch_bounds__(256) void scan_combine(
    float* __restrict__ sums_h, float* __restrict__ sums_p)
{
    int u = blockIdx.x * 256 + threadIdx.x;
    int d = u & (DINNER - 1);
    int n = (u >> 11) & (DSTATE - 1);
    int b = u >> 15;
    float hg = 0.f;
    for (int c = 0; c < NCHUNK; ++c) {
        long row = (long)(b * NCHUNK + c) * DSTATE + n;
        float p  = sums_p[row * DINNER + d];
        float hl = sums_h[row * DINNER + d];
        sums_p[row * DINNER + d] = hg;   // hstart for this chunk
        hg = p * hg + hl;
    }
}

// Pass 3: replay from hstart, fused gate, emit bf16 gated activation.
__global__ __launch_bounds__(256) void scan_pass3(
    const __bf16* __restrict__ dt16,
    const __bf16* __restrict__ xc16,
    const float* __restrict__ xdbl,
    const float* __restrict__ A_log,
    const __bf16* __restrict__ xz16,  // z half at col DINNER+d
    const float* __restrict__ sums_p, // hstart
    const float* __restrict__ Dp,
    __bf16* __restrict__ gated)       // [BL, DINNER] bf16
{
    const int d  = blockIdx.x * 256 + threadIdx.x;
    const int bc = blockIdx.y;
    const int b  = bc / NCHUNK, c = bc % NCHUNK;
    const long r0 = (long)b * SEQLEN + (long)c * LCH;

    float Ad[DSTATE];
    {
        const float4* al = (const float4*)(A_log + d * DSTATE);
#pragma unroll
        for (int q = 0; q < 4; ++q) {
            float4 v = al[q];
            Ad[q * 4 + 0] = -__expf(v.x); Ad[q * 4 + 1] = -__expf(v.y);
            Ad[q * 4 + 2] = -__expf(v.z); Ad[q * 4 + 3] = -__expf(v.w);
        }
    }

    float h[DSTATE];
    const long rowbase = (long)bc * DSTATE;
#pragma unroll
    for (int n = 0; n < DSTATE; ++n)
        h[n] = sums_p[(rowbase + n) * DINNER + d];

    const float Dv = Dp[d];

    for (int t = 0; t < LCH; ++t) {
        long r = r0 + t;
        float dtv = (float)dt16[r * DINNER + d];
        float xv  = (float)xc16[r * DINNER + d];
        float xdt = xv * dtv;
        const float4* bv = (const float4*)(xdbl + r * XDBL_N + DTRANK);
        float4 B0 = bv[0], B1 = bv[1], B2 = bv[2], B3 = bv[3];
        float4 C0 = bv[4], C1 = bv[5], C2 = bv[6], C3 = bv[7];
        const float Bn[DSTATE] = {B0.x,B0.y,B0.z,B0.w, B1.x,B1.y,B1.z,B1.w,
                                  B2.x,B2.y,B2.z,B2.w, B3.x,B3.y,B3.z,B3.w};
        const float Cn[DSTATE] = {C0.x,C0.y,C0.z,C0.w, C1.x,C1.y,C1.z,C1.w,
                                  C2.x,C2.y,C2.z,C2.w, C3.x,C3.y,C3.z,C3.w};
        float y = 0.f;
#pragma unroll
        for (int n = 0; n < DSTATE; ++n) {
            float dA = __expf(Ad[n] * dtv);
            h[n] = h[n] * dA + xdt * Bn[n];
            y += h[n] * Cn[n];
        }
        float z = (float)xz16[r * NXZ + DINNER + d];
        float yy = y + xv * Dv;
        gated[r * DINNER + d] = (__bf16)(yy * silu_f(z));
    }
}

// ---------------------------------------------------------------------------
extern "C" void kernel_launch(void* const* d_in, const int* in_sizes, int n_in,
                              void* d_out, int out_size, void* d_ws, size_t ws_size,
                              hipStream_t stream) {
    const float* x      = (const float*)d_in[0];
    const float* W_in   = (const float*)d_in[1];
    const float* conv_w = (const float*)d_in[2];
    const float* conv_b = (const float*)d_in[3];
    const float* W_x    = (const float*)d_in[4];
    const float* W_dt   = (const float*)d_in[5];
    const float* b_dt   = (const float*)d_in[6];
    const float* A_log  = (const float*)d_in[7];
    const float* Dp     = (const float*)d_in[8];
    const float* W_out  = (const float*)d_in[9];
    float* out = (float*)d_out;

    // Workspace layout (~124 MB):
    __bf16* xz16    = (__bf16*)d_ws;                    // BL*NXZ
    __bf16* xc16    = xz16 + (long)BL * NXZ;            // BL*DINNER
    __bf16* dt16    = xc16 + (long)BL * DINNER;         // BL*DINNER
    __bf16* gated16 = dt16 + (long)BL * DINNER;         // BL*DINNER
    __bf16* WoT16   = gated16 + (long)BL * DINNER;      // DINNER*DMODEL
    __bf16* WdtT16  = WoT16 + (long)DINNER * DMODEL;    // DINNER*DTRANK
    __bf16* dtlow16 = WdtT16 + (long)DINNER * DTRANK;   // BL*DTRANK
    __bf16* xb16    = dtlow16 + (long)BL * DTRANK;      // BL*DMODEL
    __bf16* WiT16   = xb16 + (long)BL * DMODEL;         // NXZ*DMODEL
    float*  xdbl    = (float*)(WiT16 + (long)NXZ * DMODEL);  // BL*96
    float*  cwT     = xdbl + (long)BL * XDBL_N;         // 4*DINNER
    float*  scratch = cwT + (long)DCONV * DINNER;       // partials / sums
    float*  sums_h  = scratch;                          // 1024*DINNER
    float*  sums_p  = scratch + (long)BATCH * NCHUNK * DSTATE * DINNER;

    dim3 blk(256);

    // 0) merged prep: cast + 3 weight transposes + conv-w transpose
    prep_kernel<<<dim3(NB_CAST + NB_WIN + NB_WOUT + NB_WDT + NB_CW), blk, 0, stream>>>(
        x, W_in, W_out, W_dt, conv_w, xb16, WiT16, WoT16, WdtT16, cwT);

    // 1) xz = x @ W_in   (MFMA bf16, bf16 store)
    gemm_bt_mfma<2><<<dim3(NXZ / 128, BL / 128), blk, 0, stream>>>(
        xb16, WiT16, xz16, BL, NXZ, DMODEL, nullptr);

    // 2) causal depthwise conv + silu -> xc16
    conv_silu_kernel<<<dim3(BL / CONVT), blk, 0, stream>>>(
        xz16, cwT, conv_b, xc16);

    // 3) x_dbl = xc @ W_x   (split-K; partials in scratch)
    gemm_xdbl_split<<<dim3(BL / 64, KSPLIT), blk, 0, stream>>>(xc16, W_x, scratch);
    xdbl_reduce<<<dim3((BL * XDBL_N) / 256), blk, 0, stream>>>(scratch, xdbl, dtlow16);

    // 4) dt = softplus(dt_low @ W_dt + b_dt)   (MFMA bf16, bf16 store)
    gemm_bt_mfma<3><<<dim3(DINNER / 128, BL / 128), blk, 0, stream>>>(
        dtlow16, WdtT16, dt16, BL, DINNER, DTRANK, b_dt);

    // 5) chunked scan: pass1 -> combine -> pass3 (+fused gate)
    {
        dim3 grid1(DINNER / 256, BATCH * NCHUNK);
        scan_pass1<<<grid1, blk, 0, stream>>>(dt16, xc16, xdbl, A_log, sums_h, sums_p);
        scan_combine<<<dim3((BATCH * DSTATE * DINNER) / 256), blk, 0, stream>>>(
            sums_h, sums_p);
        scan_pass3<<<grid1, blk, 0, stream>>>(dt16, xc16, xdbl, A_log, xz16,
                                              sums_p, Dp, gated16);
    }
    // 7) out = gated @ W_out   (MFMA bf16, fp32 out)
    gemm_bt_mfma<0><<<dim3(DMODEL / 128, BL / 128), blk, 0, stream>>>(
        gated16, WoT16, out, BL, DMODEL, DINNER, nullptr);

    (void)in_sizes; (void)n_in; (void)out_size; (void)ws_size;
}

// Round 13
// 324.561 us; speedup vs baseline: 1.2834x; 1.0785x over previous
//
#include <hip/hip_runtime.h>
#include <hip/hip_bf16.h>

// Problem constants (MambaBlock): B=2, L=2048, d_model=1024, d_inner=2048,
// d_conv=4, dt_rank=64, d_state=16. All inputs/output float32 (per reference).

#define BATCH   2
#define SEQLEN  2048
#define DMODEL  1024
#define DINNER  2048
#define DCONV   4
#define DTRANK  64
#define DSTATE  16
#define BL      (BATCH * SEQLEN)         // 4096
#define NXZ     (2 * DINNER)             // 4096
#define XDBL_N  (DTRANK + 2 * DSTATE)    // 96
#define LCH     32                       // chunk length for parallel scan
#define NCHUNK  (SEQLEN / LCH)           // 64 chunks per sequence
#define KSPLIT  8                        // split-K for the x_dbl GEMM
#define KC      (DINNER / KSPLIT)        // 256
#define ALDS    264                      // padded LDS row stride (bf16)

typedef __bf16 bf16x8 __attribute__((ext_vector_type(8)));
typedef __bf16 bf16x4 __attribute__((ext_vector_type(4)));
typedef float  floatx4 __attribute__((ext_vector_type(4)));

__device__ __forceinline__ float silu_f(float v) {
    return v / (1.f + __expf(-v));
}

// Fast softplus via native v_exp_f32/v_log_f32 (error ~1e-7, << bf16 noise).
__device__ __forceinline__ float softplus_f(float v) {
    return (v > 20.f) ? v : __logf(1.f + __expf(v));
}

// Native base-2 exp (v_exp_f32). NOTE: __exp2f does not exist in HIP device
// code (glibc macro collision) — use the amdgcn builtin.
__device__ __forceinline__ float fast_exp2(float v) {
    return __builtin_amdgcn_exp2f(v);
}

__device__ __forceinline__ void gload_lds16(const __bf16* g, __bf16* l) {
    __builtin_amdgcn_global_load_lds(
        (const __attribute__((address_space(1))) void*)g,
        (__attribute__((address_space(3))) void*)l, 16, 0, 0);
}

// ---------------------------------------------------------------------------
// MFMA bf16 GEMM (m97 structure): C[M,N] = A[M,K] * B[K,N].
// A [M,K] bf16 row-major; BT [N,K] bf16 row-major.
// EPI: 0 = fp32 store; 1 = softplus fp32; 2 = bf16 store; 3 = softplus bf16.
// Direct epilogue stores (R10's LDS restage regressed — bank aliasing).
// ---------------------------------------------------------------------------
template <int EPI>
__global__ __launch_bounds__(256) void gemm_bt_mfma(
    const __bf16* __restrict__ A,
    const __bf16* __restrict__ BT,
    void* __restrict__ Cv,
    int M, int N, int K,
    const float* __restrict__ bias)
{
    __shared__ __bf16 Asm[128 * 32];
    __shared__ __bf16 Bsm[128 * 32];

    const int tid  = threadIdx.x;
    const int w    = tid >> 6;
    const int lane = tid & 63;
    const int lrow = lane & 15;
    const int quad = lane >> 4;
    const int row0 = blockIdx.y * 128;
    const int col0 = blockIdx.x * 128;
    const int wr   = (w >> 1) * 64;
    const int wc   = (w & 1) * 64;

    const int ldr = tid >> 2;
    const int ldk = (tid & 3) * 8;
    const __bf16* gA = A  + (size_t)(row0 + ldr) * K + ldk;
    const __bf16* gB = BT + (size_t)(col0 + ldr) * K + ldk;
    const size_t half = (size_t)64 * K;
    __bf16* lA0 = Asm + w * 512;
    __bf16* lA1 = Asm + 2048 + w * 512;
    __bf16* lB0 = Bsm + w * 512;
    __bf16* lB1 = Bsm + 2048 + w * 512;

    floatx4 acc[4][4];
#pragma unroll
    for (int i = 0; i < 4; ++i)
#pragma unroll
        for (int j = 0; j < 4; ++j)
            acc[i][j] = (floatx4){0.f, 0.f, 0.f, 0.f};

    for (int k0 = 0; k0 < K; k0 += 32) {
        gload_lds16(gA, lA0);
        gload_lds16(gA + half, lA1);
        gload_lds16(gB, lB0);
        gload_lds16(gB + half, lB1);
        gA += 32; gB += 32;
        __syncthreads();

        bf16x8 af[4], bf[4];
#pragma unroll
        for (int t = 0; t < 4; ++t)
            af[t] = *(const bf16x8*)(Asm + (wr + t * 16 + lrow) * 32 + quad * 8);
#pragma unroll
        for (int t = 0; t < 4; ++t)
            bf[t] = *(const bf16x8*)(Bsm + (wc + t * 16 + lrow) * 32 + quad * 8);

#pragma unroll
        for (int ti = 0; ti < 4; ++ti)
#pragma unroll
            for (int tj = 0; tj < 4; ++tj)
                acc[ti][tj] = __builtin_amdgcn_mfma_f32_16x16x32_bf16(
                    af[ti], bf[tj], acc[ti][tj], 0, 0, 0);
        __syncthreads();
    }

#pragma unroll
    for (int ti = 0; ti < 4; ++ti) {
#pragma unroll
        for (int tj = 0; tj < 4; ++tj) {
            int col = col0 + wc + tj * 16 + lrow;
            float bv = (EPI == 1 || EPI == 3) ? bias[col] : 0.f;
#pragma unroll
            for (int r = 0; r < 4; ++r) {
                int row = row0 + wr + ti * 16 + quad * 4 + r;
                float v = acc[ti][tj][r];
                if (EPI == 1 || EPI == 3) v = softplus_f(v + bv);
                if (EPI == 2 || EPI == 3)
                    ((__bf16*)Cv)[(size_t)row * N + col] = (__bf16)v;
                else
                    ((float*)Cv)[(size_t)row * N + col] = v;
            }
        }
    }
}

// ---------------------------------------------------------------------------
// Merged preprocessing: x->bf16 cast, 3 transpose-casts, conv-w transpose.
// ---------------------------------------------------------------------------
#define NB_CAST  ((BL * DMODEL / 4) / 256)          // 4096
#define NB_WIN   ((NXZ / 32) * (DMODEL / 32))       // 4096
#define NB_WOUT  ((DMODEL / 32) * (DINNER / 32))    // 2048
#define NB_WDT   ((DINNER / 32) * (DTRANK / 32))    // 128
#define NB_CW    ((DCONV * DINNER) / 256)           // 32

__device__ __forceinline__ void transpose_tile(
    const float* __restrict__ src, __bf16* __restrict__ dst, int R, int Cc,
    int bx, int by, int tid, float* tile)
{
    int tx = tid & 31, ty = tid >> 5;   // 32 x 8
    int c0 = bx * 32, r0 = by * 32;
#pragma unroll
    for (int i = 0; i < 32; i += 8)
        tile[(ty + i) * 33 + tx] = src[(size_t)(r0 + ty + i) * Cc + c0 + tx];
    __syncthreads();
#pragma unroll
    for (int i = 0; i < 32; i += 8)
        dst[(size_t)(c0 + ty + i) * R + r0 + tx] = (__bf16)tile[tx * 33 + ty + i];
}

__global__ __launch_bounds__(256) void prep_kernel(
    const float* __restrict__ x,
    const float* __restrict__ W_in,
    const float* __restrict__ W_out,
    const float* __restrict__ W_dt,
    const float* __restrict__ conv_w,
    __bf16* __restrict__ xb16,
    __bf16* __restrict__ WiT16,
    __bf16* __restrict__ WoT16,
    __bf16* __restrict__ WdtT16,
    float* __restrict__ cwT)
{
    __shared__ float tile[32 * 33];
    const int tid = threadIdx.x;
    int bid = blockIdx.x;

    if (bid < NB_CAST) {
        long i = ((long)bid * 256 + tid) * 4;
        float4 v = *(const float4*)(x + i);
        bf16x4 o = {(__bf16)v.x, (__bf16)v.y, (__bf16)v.z, (__bf16)v.w};
        *(bf16x4*)(xb16 + i) = o;
        return;
    }
    bid -= NB_CAST;
    if (bid < NB_WIN) {
        transpose_tile(W_in, WiT16, DMODEL, NXZ,
                       bid % (NXZ / 32), bid / (NXZ / 32), tid, tile);
        return;
    }
    bid -= NB_WIN;
    if (bid < NB_WOUT) {
        transpose_tile(W_out, WoT16, DINNER, DMODEL,
                       bid % (DMODEL / 32), bid / (DMODEL / 32), tid, tile);
        return;
    }
    bid -= NB_WOUT;
    if (bid < NB_WDT) {
        transpose_tile(W_dt, WdtT16, DTRANK, DINNER,
                       bid % (DINNER / 32), bid / (DINNER / 32), tid, tile);
        return;
    }
    bid -= NB_WDT;
    {
        int i = bid * 256 + tid;                  // < DCONV*DINNER
        int k = i / DINNER, d = i % DINNER;
        cwT[i] = conv_w[d * DCONV + k];
    }
}

// ---------------------------------------------------------------------------
// Fused conv+silu + split-K x_dbl GEMM.
// Grid (BL/64, KSPLIT). Block tile: 64 rows x KC=256 channels.
// Phase 1: conv+silu from xz16 (3-row halo, zero-padded at sequence start)
//   -> LDS Acv[64][ALDS] bf16 AND global xc16 (each (row,ch) exactly once).
// Phase 2: GEMM A from LDS, W fp32 staged in Bs -> partials[kz].
// ---------------------------------------------------------------------------
__global__ __launch_bounds__(256) void xdbl_fused(
    const __bf16* __restrict__ xz16,   // [BL, NXZ], xb half
    const float* __restrict__ cwT,     // [4, DINNER]
    const float* __restrict__ cb,      // [DINNER]
    const float* __restrict__ W,       // [DINNER, 96]
    __bf16* __restrict__ xc16,         // [BL, DINNER]
    float* __restrict__ parts)         // [KSPLIT, BL, 96]
{
    __shared__ __bf16 Acv[64 * ALDS];
    __shared__ float Bs[16][97];

    const int tid  = threadIdx.x;
    const int row0 = blockIdx.x * 64;
    const int kz   = blockIdx.y;
    const int kbeg = kz * KC;

    // ---- Phase 1: conv tile -> LDS + xc16 ----
    {
        const int ct = (tid & 31) * 8;       // channel offset in chunk
        const int rt = (tid >> 5) * 8;       // row offset in tile
        const int d  = kbeg + ct;

        float wreg[DCONV][8];
#pragma unroll
        for (int k = 0; k < DCONV; ++k) {
            float4 a = *(const float4*)(cwT + k * DINNER + d);
            float4 b = *(const float4*)(cwT + k * DINNER + d + 4);
            wreg[k][0]=a.x; wreg[k][1]=a.y; wreg[k][2]=a.z; wreg[k][3]=a.w;
            wreg[k][4]=b.x; wreg[k][5]=b.y; wreg[k][6]=b.z; wreg[k][7]=b.w;
        }
        float bias8[8];
        {
            float4 a = *(const float4*)(cb + d);
            float4 b = *(const float4*)(cb + d + 4);
            bias8[0]=a.x; bias8[1]=a.y; bias8[2]=a.z; bias8[3]=a.w;
            bias8[4]=b.x; bias8[5]=b.y; bias8[6]=b.z; bias8[7]=b.w;
        }

        const bf16x8 zero = {};
        bf16x8 win[DCONV];
        const int tloc0 = (int)((row0 + rt) & (SEQLEN - 1));
#pragma unroll
        for (int j = 0; j < DCONV - 1; ++j)
            win[j] = (tloc0 - 3 + j >= 0)
                ? *(const bf16x8*)(xz16 + (size_t)(row0 + rt - 3 + j) * NXZ + d)
                : zero;

        for (int i = 0; i < 8; ++i) {
            size_t r = (size_t)row0 + rt + i;
            win[DCONV - 1] = *(const bf16x8*)(xz16 + r * NXZ + d);
            bf16x8 o;
#pragma unroll
            for (int j = 0; j < 8; ++j) {
                float acc = bias8[j];
#pragma unroll
                for (int k = 0; k < DCONV; ++k)
                    acc += (float)win[k][j] * wreg[k][j];
                o[j] = (__bf16)silu_f(acc);
            }
            *(bf16x8*)(Acv + (rt + i) * ALDS + ct) = o;
            *(bf16x8*)(xc16 + r * DINNER + d) = o;
#pragma unroll
            for (int k = 0; k < DCONV - 1; ++k)
                win[k] = win[k + 1];
        }
    }
    __syncthreads();

    // ---- Phase 2: GEMM over this K-chunk ----
    const int tr = tid >> 4;
    const int tc = tid & 15;
    const int brow = tid >> 4;
    const int bcol = (tid & 15) * 6;

    float acc[4][6] = {};

    for (int k0 = 0; k0 < KC; k0 += 16) {
#pragma unroll
        for (int j = 0; j < 6; ++j)
            Bs[brow][bcol + j] = W[(size_t)(kbeg + k0 + brow) * XDBL_N + bcol + j];
        __syncthreads();

#pragma unroll
        for (int h = 0; h < 2; ++h) {
            float a8[4][8];
#pragma unroll
            for (int i = 0; i < 4; ++i) {
                bf16x8 av = *(const bf16x8*)(Acv + (tr * 4 + i) * ALDS + k0 + h * 8);
#pragma unroll
                for (int e = 0; e < 8; ++e) a8[i][e] = (float)av[e];
            }
#pragma unroll
            for (int kk = 0; kk < 8; ++kk) {
                float b6[6];
#pragma unroll
                for (int j = 0; j < 6; ++j) b6[j] = Bs[h * 8 + kk][tc * 6 + j];
#pragma unroll
                for (int i = 0; i < 4; ++i)
#pragma unroll
                    for (int j = 0; j < 6; ++j)
                        acc[i][j] += a8[i][kk] * b6[j];
            }
        }
        __syncthreads();
    }

    const long base = (long)kz * BL * XDBL_N;
#pragma unroll
    for (int i = 0; i < 4; ++i) {
        long off = base + (long)(row0 + tr * 4 + i) * XDBL_N + tc * 6;
#pragma unroll
        for (int j = 0; j < 6; ++j)
            parts[off + j] = acc[i][j];
    }
}

// Reduce KSPLIT partials -> xdbl [BL, 96]; cols<64 also stored bf16 (dt_low).
__global__ __launch_bounds__(256) void xdbl_reduce(
    const float* __restrict__ parts, float* __restrict__ xdbl,
    __bf16* __restrict__ dtlow16)
{
    long i = (long)blockIdx.x * 256 + threadIdx.x;   // < BL*96
    float s = 0.f;
#pragma unroll
    for (int kz = 0; kz < KSPLIT; ++kz)
        s += parts[(long)kz * BL * XDBL_N + i];
    xdbl[i] = s;
    int col = (int)(i % XDBL_N);
    if (col < DTRANK) {
        long row = i / XDBL_N;
        dtlow16[row * DTRANK + col] = (__bf16)s;
    }
}

// ---------------------------------------------------------------------------
// Chunked parallel scan (dt bf16, LCH=32, exp2-prescaled decay).
// ---------------------------------------------------------------------------
__global__ __launch_bounds__(256) void scan_pass1(
    const __bf16* __restrict__ dt16,
    const __bf16* __restrict__ xc16,
    const float* __restrict__ xdbl,
    const float* __restrict__ A_log,
    float* __restrict__ sums_h,
    float* __restrict__ sums_p)
{
    const int d  = blockIdx.x * 256 + threadIdx.x;
    const int bc = blockIdx.y;
    const int b  = bc / NCHUNK, c = bc % NCHUNK;
    const long r0 = (long)b * SEQLEN + (long)c * LCH;

    float Ad[DSTATE];
    {
        const float4* al = (const float4*)(A_log + d * DSTATE);
#pragma unroll
        for (int q = 0; q < 4; ++q) {
            float4 v = al[q];
            Ad[q * 4 + 0] = -__expf(v.x) * 1.44269504f;
            Ad[q * 4 + 1] = -__expf(v.y) * 1.44269504f;
            Ad[q * 4 + 2] = -__expf(v.z) * 1.44269504f;
            Ad[q * 4 + 3] = -__expf(v.w) * 1.44269504f;
        }
    }

    float h[DSTATE] = {};
    float Pp[DSTATE];
#pragma unroll
    for (int n = 0; n < DSTATE; ++n) Pp[n] = 1.f;

    for (int t = 0; t < LCH; ++t) {
        long r = r0 + t;
        float dtv = (float)dt16[r * DINNER + d];
        float xv  = (float)xc16[r * DINNER + d];
        float xdt = xv * dtv;
        const float4* bv = (const float4*)(xdbl + r * XDBL_N + DTRANK);
        float4 B0 = bv[0], B1 = bv[1], B2 = bv[2], B3 = bv[3];
        const float Bn[DSTATE] = {B0.x,B0.y,B0.z,B0.w, B1.x,B1.y,B1.z,B1.w,
                                  B2.x,B2.y,B2.z,B2.w, B3.x,B3.y,B3.z,B3.w};
#pragma unroll
        for (int n = 0; n < DSTATE; ++n) {
            float dA = fast_exp2(Ad[n] * dtv);
            h[n] = h[n] * dA + xdt * Bn[n];
            Pp[n] *= dA;
        }
    }

    const long rowbase = (long)bc * DSTATE;
#pragma unroll
    for (int n = 0; n < DSTATE; ++n) {
        sums_h[(rowbase + n) * DINNER + d] = h[n];
        sums_p[(rowbase + n) * DINNER + d] = Pp[n];
    }
}

__global__ __launch_bounds__(256) void scan_combine(
    float* __restrict__ sums_h, float* __restrict__ sums_p)
{
    int u = blockIdx.x * 256 + threadIdx.x;
    int d = u & (DINNER - 1);
    int n = (u >> 11) & (DSTATE - 1);
    int b = u >> 15;
    float hg = 0.f;
    for (int c = 0; c < NCHUNK; ++c) {
        long row = (long)(b * NCHUNK + c) * DSTATE + n;
        float p  = sums_p[row * DINNER + d];
        float hl = sums_h[row * DINNER + d];
        sums_p[row * DINNER + d] = hg;   // hstart for this chunk
        hg = p * hg + hl;
    }
}

// Pass 3: replay from hstart, fused gate, emit bf16 gated activation.
__global__ __launch_bounds__(256) void scan_pass3(
    const __bf16* __restrict__ dt16,
    const __bf16* __restrict__ xc16,
    const float* __restrict__ xdbl,
    const float* __restrict__ A_log,
    const __bf16* __restrict__ xz16,  // z half at col DINNER+d
    const float* __restrict__ sums_p, // hstart
    const float* __restrict__ Dp,
    __bf16* __restrict__ gated)       // [BL, DINNER] bf16
{
    const int d  = blockIdx.x * 256 + threadIdx.x;
    const int bc = blockIdx.y;
    const int b  = bc / NCHUNK, c = bc % NCHUNK;
    const long r0 = (long)b * SEQLEN + (long)c * LCH;

    float Ad[DSTATE];
    {
        const float4* al = (const float4*)(A_log + d * DSTATE);
#pragma unroll
        for (int q = 0; q < 4; ++q) {
            float4 v = al[q];
            Ad[q * 4 + 0] = -__expf(v.x) * 1.44269504f;
            Ad[q * 4 + 1] = -__expf(v.y) * 1.44269504f;
            Ad[q * 4 + 2] = -__expf(v.z) * 1.44269504f;
            Ad[q * 4 + 3] = -__expf(v.w) * 1.44269504f;
        }
    }

    float h[DSTATE];
    const long rowbase = (long)bc * DSTATE;
#pragma unroll
    for (int n = 0; n < DSTATE; ++n)
        h[n] = sums_p[(rowbase + n) * DINNER + d];

    const float Dv = Dp[d];

    for (int t = 0; t < LCH; ++t) {
        long r = r0 + t;
        float dtv = (float)dt16[r * DINNER + d];
        float xv  = (float)xc16[r * DINNER + d];
        float xdt = xv * dtv;
        const float4* bv = (const float4*)(xdbl + r * XDBL_N + DTRANK);
        float4 B0 = bv[0], B1 = bv[1], B2 = bv[2], B3 = bv[3];
        float4 C0 = bv[4], C1 = bv[5], C2 = bv[6], C3 = bv[7];
        const float Bn[DSTATE] = {B0.x,B0.y,B0.z,B0.w, B1.x,B1.y,B1.z,B1.w,
                                  B2.x,B2.y,B2.z,B2.w, B3.x,B3.y,B3.z,B3.w};
        const float Cn[DSTATE] = {C0.x,C0.y,C0.z,C0.w, C1.x,C1.y,C1.z,C1.w,
                                  C2.x,C2.y,C2.z,C2.w, C3.x,C3.y,C3.z,C3.w};
        float y = 0.f;
#pragma unroll
        for (int n = 0; n < DSTATE; ++n) {
            float dA = fast_exp2(Ad[n] * dtv);
            h[n] = h[n] * dA + xdt * Bn[n];
            y += h[n] * Cn[n];
        }
        float z = (float)xz16[r * NXZ + DINNER + d];
        float yy = y + xv * Dv;
        gated[r * DINNER + d] = (__bf16)(yy * silu_f(z));
    }
}

// ---------------------------------------------------------------------------
extern "C" void kernel_launch(void* const* d_in, const int* in_sizes, int n_in,
                              void* d_out, int out_size, void* d_ws, size_t ws_size,
                              hipStream_t stream) {
    const float* x      = (const float*)d_in[0];
    const float* W_in   = (const float*)d_in[1];
    const float* conv_w = (const float*)d_in[2];
    const float* conv_b = (const float*)d_in[3];
    const float* W_x    = (const float*)d_in[4];
    const float* W_dt   = (const float*)d_in[5];
    const float* b_dt   = (const float*)d_in[6];
    const float* A_log  = (const float*)d_in[7];
    const float* Dp     = (const float*)d_in[8];
    const float* W_out  = (const float*)d_in[9];
    float* out = (float*)d_out;

    // Workspace layout (~141 MB):
    __bf16* xz16    = (__bf16*)d_ws;                    // BL*NXZ
    __bf16* xc16    = xz16 + (long)BL * NXZ;            // BL*DINNER
    __bf16* dt16    = xc16 + (long)BL * DINNER;         // BL*DINNER
    __bf16* gated16 = dt16 + (long)BL * DINNER;         // BL*DINNER
    __bf16* WoT16   = gated16 + (long)BL * DINNER;      // DINNER*DMODEL
    __bf16* WdtT16  = WoT16 + (long)DINNER * DMODEL;    // DINNER*DTRANK
    __bf16* dtlow16 = WdtT16 + (long)DINNER * DTRANK;   // BL*DTRANK
    __bf16* xb16    = dtlow16 + (long)BL * DTRANK;      // BL*DMODEL
    __bf16* WiT16   = xb16 + (long)BL * DMODEL;         // NXZ*DMODEL
    float*  xdbl    = (float*)(WiT16 + (long)NXZ * DMODEL);  // BL*96
    float*  cwT     = xdbl + (long)BL * XDBL_N;         // 4*DINNER
    float*  scratch = cwT + (long)DCONV * DINNER;       // partials, then sums
    float*  sums_h  = scratch;                          // 2048*DINNER
    float*  sums_p  = scratch + (long)BATCH * NCHUNK * DSTATE * DINNER;

    dim3 blk(256);

    // 0) merged prep: cast + 3 weight transposes + conv-w transpose
    prep_kernel<<<dim3(NB_CAST + NB_WIN + NB_WOUT + NB_WDT + NB_CW), blk, 0, stream>>>(
        x, W_in, W_out, W_dt, conv_w, xb16, WiT16, WoT16, WdtT16, cwT);

    // 1) xz = x @ W_in   (MFMA bf16, bf16 store)
    gemm_bt_mfma<2><<<dim3(NXZ / 128, BL / 128), blk, 0, stream>>>(
        xb16, WiT16, xz16, BL, NXZ, DMODEL, nullptr);

    // 2+3) fused conv+silu (-> xc16) + split-K x_dbl partials
    xdbl_fused<<<dim3(BL / 64, KSPLIT), blk, 0, stream>>>(
        xz16, cwT, conv_b, W_x, xc16, scratch);
    xdbl_reduce<<<dim3((BL * XDBL_N) / 256), blk, 0, stream>>>(scratch, xdbl, dtlow16);

    // 4) dt = softplus(dt_low @ W_dt + b_dt)   (MFMA bf16, bf16 store)
    gemm_bt_mfma<3><<<dim3(DINNER / 128, BL / 128), blk, 0, stream>>>(
        dtlow16, WdtT16, dt16, BL, DINNER, DTRANK, b_dt);

    // 5) chunked scan: pass1 -> combine -> pass3 (+fused gate)
    {
        dim3 grid1(DINNER / 256, BATCH * NCHUNK);
        scan_pass1<<<grid1, blk, 0, stream>>>(dt16, xc16, xdbl, A_log, sums_h, sums_p);
        scan_combine<<<dim3((BATCH * DSTATE * DINNER) / 256), blk, 0, stream>>>(
            sums_h, sums_p);
        scan_pass3<<<grid1, blk, 0, stream>>>(dt16, xc16, xdbl, A_log, xz16,
                                              sums_p, Dp, gated16);
    }
    // 7) out = gated @ W_out   (MFMA bf16, fp32 out)
    gemm_bt_mfma<0><<<dim3(DMODEL / 128, BL / 128), blk, 0, stream>>>(
        gated16, WoT16, out, BL, DMODEL, DINNER, nullptr);

    (void)in_sizes; (void)n_in; (void)out_size; (void)ws_size;
}

// Round 14
// 314.456 us; speedup vs baseline: 1.3247x; 1.0321x over previous
//
#include <hip/hip_runtime.h>
#include <hip/hip_bf16.h>

// Problem constants (MambaBlock): B=2, L=2048, d_model=1024, d_inner=2048,
// d_conv=4, dt_rank=64, d_state=16. All inputs/output float32 (per reference).

#define BATCH   2
#define SEQLEN  2048
#define DMODEL  1024
#define DINNER  2048
#define DCONV   4
#define DTRANK  64
#define DSTATE  16
#define BL      (BATCH * SEQLEN)         // 4096
#define NXZ     (2 * DINNER)             // 4096
#define XDBL_N  (DTRANK + 2 * DSTATE)    // 96
#define LCH     32                       // chunk length for parallel scan
#define NCHUNK  (SEQLEN / LCH)           // 64 chunks per sequence
#define KSPLIT  8                        // split-K for the x_dbl GEMM
#define KC      (DINNER / KSPLIT)        // 256
#define ALDS    264                      // padded LDS row stride (bf16)

typedef __bf16 bf16x8 __attribute__((ext_vector_type(8)));
typedef __bf16 bf16x4 __attribute__((ext_vector_type(4)));
typedef float  floatx4 __attribute__((ext_vector_type(4)));

__device__ __forceinline__ float silu_f(float v) {
    return v / (1.f + __expf(-v));
}

// Fast softplus via native v_exp_f32/v_log_f32 (error ~1e-7, << bf16 noise).
__device__ __forceinline__ float softplus_f(float v) {
    return (v > 20.f) ? v : __logf(1.f + __expf(v));
}

// Native base-2 exp (v_exp_f32). __exp2f collides with a glibc macro.
__device__ __forceinline__ float fast_exp2(float v) {
    return __builtin_amdgcn_exp2f(v);
}

__device__ __forceinline__ void gload_lds16(const __bf16* g, __bf16* l) {
    __builtin_amdgcn_global_load_lds(
        (const __attribute__((address_space(1))) void*)g,
        (__attribute__((address_space(3))) void*)l, 16, 0, 0);
}

// ---------------------------------------------------------------------------
// MFMA bf16 GEMM, 128x128 tile (m97 structure): used for the big xz GEMM.
// EPI: 0 = fp32 store; 1 = softplus fp32; 2 = bf16 store; 3 = softplus bf16.
// ---------------------------------------------------------------------------
template <int EPI>
__global__ __launch_bounds__(256) void gemm_bt_mfma(
    const __bf16* __restrict__ A,
    const __bf16* __restrict__ BT,
    void* __restrict__ Cv,
    int M, int N, int K,
    const float* __restrict__ bias)
{
    __shared__ __bf16 Asm[128 * 32];
    __shared__ __bf16 Bsm[128 * 32];

    const int tid  = threadIdx.x;
    const int w    = tid >> 6;
    const int lane = tid & 63;
    const int lrow = lane & 15;
    const int quad = lane >> 4;
    const int row0 = blockIdx.y * 128;
    const int col0 = blockIdx.x * 128;
    const int wr   = (w >> 1) * 64;
    const int wc   = (w & 1) * 64;

    const int ldr = tid >> 2;
    const int ldk = (tid & 3) * 8;
    const __bf16* gA = A  + (size_t)(row0 + ldr) * K + ldk;
    const __bf16* gB = BT + (size_t)(col0 + ldr) * K + ldk;
    const size_t half = (size_t)64 * K;
    __bf16* lA0 = Asm + w * 512;
    __bf16* lA1 = Asm + 2048 + w * 512;
    __bf16* lB0 = Bsm + w * 512;
    __bf16* lB1 = Bsm + 2048 + w * 512;

    floatx4 acc[4][4];
#pragma unroll
    for (int i = 0; i < 4; ++i)
#pragma unroll
        for (int j = 0; j < 4; ++j)
            acc[i][j] = (floatx4){0.f, 0.f, 0.f, 0.f};

    for (int k0 = 0; k0 < K; k0 += 32) {
        gload_lds16(gA, lA0);
        gload_lds16(gA + half, lA1);
        gload_lds16(gB, lB0);
        gload_lds16(gB + half, lB1);
        gA += 32; gB += 32;
        __syncthreads();

        bf16x8 af[4], bf[4];
#pragma unroll
        for (int t = 0; t < 4; ++t)
            af[t] = *(const bf16x8*)(Asm + (wr + t * 16 + lrow) * 32 + quad * 8);
#pragma unroll
        for (int t = 0; t < 4; ++t)
            bf[t] = *(const bf16x8*)(Bsm + (wc + t * 16 + lrow) * 32 + quad * 8);

#pragma unroll
        for (int ti = 0; ti < 4; ++ti)
#pragma unroll
            for (int tj = 0; tj < 4; ++tj)
                acc[ti][tj] = __builtin_amdgcn_mfma_f32_16x16x32_bf16(
                    af[ti], bf[tj], acc[ti][tj], 0, 0, 0);
        __syncthreads();
    }

#pragma unroll
    for (int ti = 0; ti < 4; ++ti) {
#pragma unroll
        for (int tj = 0; tj < 4; ++tj) {
            int col = col0 + wc + tj * 16 + lrow;
            float bv = (EPI == 1 || EPI == 3) ? bias[col] : 0.f;
#pragma unroll
            for (int r = 0; r < 4; ++r) {
                int row = row0 + wr + ti * 16 + quad * 4 + r;
                float v = acc[ti][tj][r];
                if (EPI == 1 || EPI == 3) v = softplus_f(v + bv);
                if (EPI == 2 || EPI == 3)
                    ((__bf16*)Cv)[(size_t)row * N + col] = (__bf16)v;
                else
                    ((float*)Cv)[(size_t)row * N + col] = v;
            }
        }
    }
}

// ---------------------------------------------------------------------------
// MFMA bf16 GEMM, 64x128 tile — occupancy variant for small-K / small-N GEMMs
// (out GEMM: 1 blk/CU with 128-tile; dt GEMM: K=64, acc mostly dead).
// 4 waves side by side: wave w = rows 0..63 x cols w*32..w*32+31, acc 4x2.
// ---------------------------------------------------------------------------
template <int EPI>
__global__ __launch_bounds__(256) void gemm_r64(
    const __bf16* __restrict__ A,
    const __bf16* __restrict__ BT,
    void* __restrict__ Cv,
    int M, int N, int K,
    const float* __restrict__ bias)
{
    __shared__ __bf16 Asm[64 * 32];
    __shared__ __bf16 Bsm[128 * 32];

    const int tid  = threadIdx.x;
    const int w    = tid >> 6;
    const int lane = tid & 63;
    const int lrow = lane & 15;
    const int quad = lane >> 4;
    const int row0 = blockIdx.y * 64;
    const int col0 = blockIdx.x * 128;
    const int wc   = w * 32;

    const int ldr = tid >> 2;
    const int ldk = (tid & 3) * 8;
    const __bf16* gA = A  + (size_t)(row0 + ldr) * K + ldk;
    const __bf16* gB = BT + (size_t)(col0 + ldr) * K + ldk;
    const size_t half = (size_t)64 * K;
    __bf16* lA0 = Asm + w * 512;
    __bf16* lB0 = Bsm + w * 512;
    __bf16* lB1 = Bsm + 2048 + w * 512;

    floatx4 acc[4][2];
#pragma unroll
    for (int i = 0; i < 4; ++i)
#pragma unroll
        for (int j = 0; j < 2; ++j)
            acc[i][j] = (floatx4){0.f, 0.f, 0.f, 0.f};

    for (int k0 = 0; k0 < K; k0 += 32) {
        gload_lds16(gA, lA0);
        gload_lds16(gB, lB0);
        gload_lds16(gB + half, lB1);
        gA += 32; gB += 32;
        __syncthreads();

        bf16x8 af[4], bf[2];
#pragma unroll
        for (int t = 0; t < 4; ++t)
            af[t] = *(const bf16x8*)(Asm + (t * 16 + lrow) * 32 + quad * 8);
#pragma unroll
        for (int u = 0; u < 2; ++u)
            bf[u] = *(const bf16x8*)(Bsm + (wc + u * 16 + lrow) * 32 + quad * 8);

#pragma unroll
        for (int ti = 0; ti < 4; ++ti)
#pragma unroll
            for (int tj = 0; tj < 2; ++tj)
                acc[ti][tj] = __builtin_amdgcn_mfma_f32_16x16x32_bf16(
                    af[ti], bf[tj], acc[ti][tj], 0, 0, 0);
        __syncthreads();
    }

#pragma unroll
    for (int ti = 0; ti < 4; ++ti) {
#pragma unroll
        for (int tj = 0; tj < 2; ++tj) {
            int col = col0 + wc + tj * 16 + lrow;
            float bv = (EPI == 1 || EPI == 3) ? bias[col] : 0.f;
#pragma unroll
            for (int r = 0; r < 4; ++r) {
                int row = row0 + ti * 16 + quad * 4 + r;
                float v = acc[ti][tj][r];
                if (EPI == 1 || EPI == 3) v = softplus_f(v + bv);
                if (EPI == 2 || EPI == 3)
                    ((__bf16*)Cv)[(size_t)row * N + col] = (__bf16)v;
                else
                    ((float*)Cv)[(size_t)row * N + col] = v;
            }
        }
    }
}

// ---------------------------------------------------------------------------
// Merged preprocessing: x->bf16 cast, 3 transpose-casts, conv-w transpose.
// ---------------------------------------------------------------------------
#define NB_CAST  ((BL * DMODEL / 4) / 256)          // 4096
#define NB_WIN   ((NXZ / 32) * (DMODEL / 32))       // 4096
#define NB_WOUT  ((DMODEL / 32) * (DINNER / 32))    // 2048
#define NB_WDT   ((DINNER / 32) * (DTRANK / 32))    // 128
#define NB_CW    ((DCONV * DINNER) / 256)           // 32

__device__ __forceinline__ void transpose_tile(
    const float* __restrict__ src, __bf16* __restrict__ dst, int R, int Cc,
    int bx, int by, int tid, float* tile)
{
    int tx = tid & 31, ty = tid >> 5;   // 32 x 8
    int c0 = bx * 32, r0 = by * 32;
#pragma unroll
    for (int i = 0; i < 32; i += 8)
        tile[(ty + i) * 33 + tx] = src[(size_t)(r0 + ty + i) * Cc + c0 + tx];
    __syncthreads();
#pragma unroll
    for (int i = 0; i < 32; i += 8)
        dst[(size_t)(c0 + ty + i) * R + r0 + tx] = (__bf16)tile[tx * 33 + ty + i];
}

__global__ __launch_bounds__(256) void prep_kernel(
    const float* __restrict__ x,
    const float* __restrict__ W_in,
    const float* __restrict__ W_out,
    const float* __restrict__ W_dt,
    const float* __restrict__ conv_w,
    __bf16* __restrict__ xb16,
    __bf16* __restrict__ WiT16,
    __bf16* __restrict__ WoT16,
    __bf16* __restrict__ WdtT16,
    float* __restrict__ cwT)
{
    __shared__ float tile[32 * 33];
    const int tid = threadIdx.x;
    int bid = blockIdx.x;

    if (bid < NB_CAST) {
        long i = ((long)bid * 256 + tid) * 4;
        float4 v = *(const float4*)(x + i);
        bf16x4 o = {(__bf16)v.x, (__bf16)v.y, (__bf16)v.z, (__bf16)v.w};
        *(bf16x4*)(xb16 + i) = o;
        return;
    }
    bid -= NB_CAST;
    if (bid < NB_WIN) {
        transpose_tile(W_in, WiT16, DMODEL, NXZ,
                       bid % (NXZ / 32), bid / (NXZ / 32), tid, tile);
        return;
    }
    bid -= NB_WIN;
    if (bid < NB_WOUT) {
        transpose_tile(W_out, WoT16, DINNER, DMODEL,
                       bid % (DMODEL / 32), bid / (DMODEL / 32), tid, tile);
        return;
    }
    bid -= NB_WOUT;
    if (bid < NB_WDT) {
        transpose_tile(W_dt, WdtT16, DTRANK, DINNER,
                       bid % (DINNER / 32), bid / (DINNER / 32), tid, tile);
        return;
    }
    bid -= NB_WDT;
    {
        int i = bid * 256 + tid;                  // < DCONV*DINNER
        int k = i / DINNER, d = i % DINNER;
        cwT[i] = conv_w[d * DCONV + k];
    }
}

// ---------------------------------------------------------------------------
// Fused conv+silu + split-K x_dbl GEMM.
// Grid (BL/64, KSPLIT). Block tile: 64 rows x KC=256 channels.
// ---------------------------------------------------------------------------
__global__ __launch_bounds__(256) void xdbl_fused(
    const __bf16* __restrict__ xz16,   // [BL, NXZ], xb half
    const float* __restrict__ cwT,     // [4, DINNER]
    const float* __restrict__ cb,      // [DINNER]
    const float* __restrict__ W,       // [DINNER, 96]
    __bf16* __restrict__ xc16,         // [BL, DINNER]
    float* __restrict__ parts)         // [KSPLIT, BL, 96]
{
    __shared__ __bf16 Acv[64 * ALDS];
    __shared__ float Bs[16][97];

    const int tid  = threadIdx.x;
    const int row0 = blockIdx.x * 64;
    const int kz   = blockIdx.y;
    const int kbeg = kz * KC;

    // ---- Phase 1: conv tile -> LDS + xc16 ----
    {
        const int ct = (tid & 31) * 8;
        const int rt = (tid >> 5) * 8;
        const int d  = kbeg + ct;

        float wreg[DCONV][8];
#pragma unroll
        for (int k = 0; k < DCONV; ++k) {
            float4 a = *(const float4*)(cwT + k * DINNER + d);
            float4 b = *(const float4*)(cwT + k * DINNER + d + 4);
            wreg[k][0]=a.x; wreg[k][1]=a.y; wreg[k][2]=a.z; wreg[k][3]=a.w;
            wreg[k][4]=b.x; wreg[k][5]=b.y; wreg[k][6]=b.z; wreg[k][7]=b.w;
        }
        float bias8[8];
        {
            float4 a = *(const float4*)(cb + d);
            float4 b = *(const float4*)(cb + d + 4);
            bias8[0]=a.x; bias8[1]=a.y; bias8[2]=a.z; bias8[3]=a.w;
            bias8[4]=b.x; bias8[5]=b.y; bias8[6]=b.z; bias8[7]=b.w;
        }

        const bf16x8 zero = {};
        bf16x8 win[DCONV];
        const int tloc0 = (int)((row0 + rt) & (SEQLEN - 1));
#pragma unroll
        for (int j = 0; j < DCONV - 1; ++j)
            win[j] = (tloc0 - 3 + j >= 0)
                ? *(const bf16x8*)(xz16 + (size_t)(row0 + rt - 3 + j) * NXZ + d)
                : zero;

        for (int i = 0; i < 8; ++i) {
            size_t r = (size_t)row0 + rt + i;
            win[DCONV - 1] = *(const bf16x8*)(xz16 + r * NXZ + d);
            bf16x8 o;
#pragma unroll
            for (int j = 0; j < 8; ++j) {
                float acc = bias8[j];
#pragma unroll
                for (int k = 0; k < DCONV; ++k)
                    acc += (float)win[k][j] * wreg[k][j];
                o[j] = (__bf16)silu_f(acc);
            }
            *(bf16x8*)(Acv + (rt + i) * ALDS + ct) = o;
            *(bf16x8*)(xc16 + r * DINNER + d) = o;
#pragma unroll
            for (int k = 0; k < DCONV - 1; ++k)
                win[k] = win[k + 1];
        }
    }
    __syncthreads();

    // ---- Phase 2: GEMM over this K-chunk ----
    const int tr = tid >> 4;
    const int tc = tid & 15;
    const int brow = tid >> 4;
    const int bcol = (tid & 15) * 6;

    float acc[4][6] = {};

    for (int k0 = 0; k0 < KC; k0 += 16) {
#pragma unroll
        for (int j = 0; j < 6; ++j)
            Bs[brow][bcol + j] = W[(size_t)(kbeg + k0 + brow) * XDBL_N + bcol + j];
        __syncthreads();

#pragma unroll
        for (int h = 0; h < 2; ++h) {
            float a8[4][8];
#pragma unroll
            for (int i = 0; i < 4; ++i) {
                bf16x8 av = *(const bf16x8*)(Acv + (tr * 4 + i) * ALDS + k0 + h * 8);
#pragma unroll
                for (int e = 0; e < 8; ++e) a8[i][e] = (float)av[e];
            }
#pragma unroll
            for (int kk = 0; kk < 8; ++kk) {
                float b6[6];
#pragma unroll
                for (int j = 0; j < 6; ++j) b6[j] = Bs[h * 8 + kk][tc * 6 + j];
#pragma unroll
                for (int i = 0; i < 4; ++i)
#pragma unroll
                    for (int j = 0; j < 6; ++j)
                        acc[i][j] += a8[i][kk] * b6[j];
            }
        }
        __syncthreads();
    }

    const long base = (long)kz * BL * XDBL_N;
#pragma unroll
    for (int i = 0; i < 4; ++i) {
        long off = base + (long)(row0 + tr * 4 + i) * XDBL_N + tc * 6;
#pragma unroll
        for (int j = 0; j < 6; ++j)
            parts[off + j] = acc[i][j];
    }
}

// Reduce KSPLIT partials -> xdbl [BL, 96]; cols<64 also stored bf16 (dt_low).
__global__ __launch_bounds__(256) void xdbl_reduce(
    const float* __restrict__ parts, float* __restrict__ xdbl,
    __bf16* __restrict__ dtlow16)
{
    long i = (long)blockIdx.x * 256 + threadIdx.x;   // < BL*96
    float s = 0.f;
#pragma unroll
    for (int kz = 0; kz < KSPLIT; ++kz)
        s += parts[(long)kz * BL * XDBL_N + i];
    xdbl[i] = s;
    int col = (int)(i % XDBL_N);
    if (col < DTRANK) {
        long row = i / XDBL_N;
        dtlow16[row * DTRANK + col] = (__bf16)s;
    }
}

// ---------------------------------------------------------------------------
// Chunked parallel scan (dt bf16, LCH=32, exp2-prescaled decay).
// ---------------------------------------------------------------------------
__global__ __launch_bounds__(256) void scan_pass1(
    const __bf16* __restrict__ dt16,
    const __bf16* __restrict__ xc16,
    const float* __restrict__ xdbl,
    const float* __restrict__ A_log,
    float* __restrict__ sums_h,
    float* __restrict__ sums_p)
{
    const int d  = blockIdx.x * 256 + threadIdx.x;
    const int bc = blockIdx.y;
    const int b  = bc / NCHUNK, c = bc % NCHUNK;
    const long r0 = (long)b * SEQLEN + (long)c * LCH;

    float Ad[DSTATE];
    {
        const float4* al = (const float4*)(A_log + d * DSTATE);
#pragma unroll
        for (int q = 0; q < 4; ++q) {
            float4 v = al[q];
            Ad[q * 4 + 0] = -__expf(v.x) * 1.44269504f;
            Ad[q * 4 + 1] = -__expf(v.y) * 1.44269504f;
            Ad[q * 4 + 2] = -__expf(v.z) * 1.44269504f;
            Ad[q * 4 + 3] = -__expf(v.w) * 1.44269504f;
        }
    }

    float h[DSTATE] = {};
    float Pp[DSTATE];
#pragma unroll
    for (int n = 0; n < DSTATE; ++n) Pp[n] = 1.f;

    for (int t = 0; t < LCH; ++t) {
        long r = r0 + t;
        float dtv = (float)dt16[r * DINNER + d];
        float xv  = (float)xc16[r * DINNER + d];
        float xdt = xv * dtv;
        const float4* bv = (const float4*)(xdbl + r * XDBL_N + DTRANK);
        float4 B0 = bv[0], B1 = bv[1], B2 = bv[2], B3 = bv[3];
        const float Bn[DSTATE] = {B0.x,B0.y,B0.z,B0.w, B1.x,B1.y,B1.z,B1.w,
                                  B2.x,B2.y,B2.z,B2.w, B3.x,B3.y,B3.z,B3.w};
#pragma unroll
        for (int n = 0; n < DSTATE; ++n) {
            float dA = fast_exp2(Ad[n] * dtv);
            h[n] = h[n] * dA + xdt * Bn[n];
            Pp[n] *= dA;
        }
    }

    const long rowbase = (long)bc * DSTATE;
#pragma unroll
    for (int n = 0; n < DSTATE; ++n) {
        sums_h[(rowbase + n) * DINNER + d] = h[n];
        sums_p[(rowbase + n) * DINNER + d] = Pp[n];
    }
}

__global__ __launch_bounds__(256) void scan_combine(
    float* __restrict__ sums_h, float* __restrict__ sums_p)
{
    int u = blockIdx.x * 256 + threadIdx.x;
    int d = u & (DINNER - 1);
    int n = (u >> 11) & (DSTATE - 1);
    int b = u >> 15;
    float hg = 0.f;
    for (int c = 0; c < NCHUNK; ++c) {
        long row = (long)(b * NCHUNK + c) * DSTATE + n;
        float p  = sums_p[row * DINNER + d];
        float hl = sums_h[row * DINNER + d];
        sums_p[row * DINNER + d] = hg;   // hstart for this chunk
        hg = p * hg + hl;
    }
}

// Pass 3: replay from hstart, fused gate, emit bf16 gated activation.
__global__ __launch_bounds__(256) void scan_pass3(
    const __bf16* __restrict__ dt16,
    const __bf16* __restrict__ xc16,
    const float* __restrict__ xdbl,
    const float* __restrict__ A_log,
    const __bf16* __restrict__ xz16,  // z half at col DINNER+d
    const float* __restrict__ sums_p, // hstart
    const float* __restrict__ Dp,
    __bf16* __restrict__ gated)       // [BL, DINNER] bf16
{
    const int d  = blockIdx.x * 256 + threadIdx.x;
    const int bc = blockIdx.y;
    const int b  = bc / NCHUNK, c = bc % NCHUNK;
    const long r0 = (long)b * SEQLEN + (long)c * LCH;

    float Ad[DSTATE];
    {
        const float4* al = (const float4*)(A_log + d * DSTATE);
#pragma unroll
        for (int q = 0; q < 4; ++q) {
            float4 v = al[q];
            Ad[q * 4 + 0] = -__expf(v.x) * 1.44269504f;
            Ad[q * 4 + 1] = -__expf(v.y) * 1.44269504f;
            Ad[q * 4 + 2] = -__expf(v.z) * 1.44269504f;
            Ad[q * 4 + 3] = -__expf(v.w) * 1.44269504f;
        }
    }

    float h[DSTATE];
    const long rowbase = (long)bc * DSTATE;
#pragma unroll
    for (int n = 0; n < DSTATE; ++n)
        h[n] = sums_p[(rowbase + n) * DINNER + d];

    const float Dv = Dp[d];

    for (int t = 0; t < LCH; ++t) {
        long r = r0 + t;
        float dtv = (float)dt16[r * DINNER + d];
        float xv  = (float)xc16[r * DINNER + d];
        float xdt = xv * dtv;
        const float4* bv = (const float4*)(xdbl + r * XDBL_N + DTRANK);
        float4 B0 = bv[0], B1 = bv[1], B2 = bv[2], B3 = bv[3];
        float4 C0 = bv[4], C1 = bv[5], C2 = bv[6], C3 = bv[7];
        const float Bn[DSTATE] = {B0.x,B0.y,B0.z,B0.w, B1.x,B1.y,B1.z,B1.w,
                                  B2.x,B2.y,B2.z,B2.w, B3.x,B3.y,B3.z,B3.w};
        const float Cn[DSTATE] = {C0.x,C0.y,C0.z,C0.w, C1.x,C1.y,C1.z,C1.w,
                                  C2.x,C2.y,C2.z,C2.w, C3.x,C3.y,C3.z,C3.w};
        float y = 0.f;
#pragma unroll
        for (int n = 0; n < DSTATE; ++n) {
            float dA = fast_exp2(Ad[n] * dtv);
            h[n] = h[n] * dA + xdt * Bn[n];
            y += h[n] * Cn[n];
        }
        float z = (float)xz16[r * NXZ + DINNER + d];
        float yy = y + xv * Dv;
        gated[r * DINNER + d] = (__bf16)(yy * silu_f(z));
    }
}

// ---------------------------------------------------------------------------
extern "C" void kernel_launch(void* const* d_in, const int* in_sizes, int n_in,
                              void* d_out, int out_size, void* d_ws, size_t ws_size,
                              hipStream_t stream) {
    const float* x      = (const float*)d_in[0];
    const float* W_in   = (const float*)d_in[1];
    const float* conv_w = (const float*)d_in[2];
    const float* conv_b = (const float*)d_in[3];
    const float* W_x    = (const float*)d_in[4];
    const float* W_dt   = (const float*)d_in[5];
    const float* b_dt   = (const float*)d_in[6];
    const float* A_log  = (const float*)d_in[7];
    const float* Dp     = (const float*)d_in[8];
    const float* W_out  = (const float*)d_in[9];
    float* out = (float*)d_out;

    // Workspace layout (~141 MB):
    __bf16* xz16    = (__bf16*)d_ws;                    // BL*NXZ
    __bf16* xc16    = xz16 + (long)BL * NXZ;            // BL*DINNER
    __bf16* dt16    = xc16 + (long)BL * DINNER;         // BL*DINNER
    __bf16* gated16 = dt16 + (long)BL * DINNER;         // BL*DINNER
    __bf16* WoT16   = gated16 + (long)BL * DINNER;      // DINNER*DMODEL
    __bf16* WdtT16  = WoT16 + (long)DINNER * DMODEL;    // DINNER*DTRANK
    __bf16* dtlow16 = WdtT16 + (long)DINNER * DTRANK;   // BL*DTRANK
    __bf16* xb16    = dtlow16 + (long)BL * DTRANK;      // BL*DMODEL
    __bf16* WiT16   = xb16 + (long)BL * DMODEL;         // NXZ*DMODEL
    float*  xdbl    = (float*)(WiT16 + (long)NXZ * DMODEL);  // BL*96
    float*  cwT     = xdbl + (long)BL * XDBL_N;         // 4*DINNER
    float*  scratch = cwT + (long)DCONV * DINNER;       // partials, then sums
    float*  sums_h  = scratch;                          // 2048*DINNER
    float*  sums_p  = scratch + (long)BATCH * NCHUNK * DSTATE * DINNER;

    dim3 blk(256);

    // 0) merged prep: cast + 3 weight transposes + conv-w transpose
    prep_kernel<<<dim3(NB_CAST + NB_WIN + NB_WOUT + NB_WDT + NB_CW), blk, 0, stream>>>(
        x, W_in, W_out, W_dt, conv_w, xb16, WiT16, WoT16, WdtT16, cwT);

    // 1) xz = x @ W_in   (MFMA bf16, 128x128 tile, bf16 store)
    gemm_bt_mfma<2><<<dim3(NXZ / 128, BL / 128), blk, 0, stream>>>(
        xb16, WiT16, xz16, BL, NXZ, DMODEL, nullptr);

    // 2+3) fused conv+silu (-> xc16) + split-K x_dbl partials
    xdbl_fused<<<dim3(BL / 64, KSPLIT), blk, 0, stream>>>(
        xz16, cwT, conv_b, W_x, xc16, scratch);
    xdbl_reduce<<<dim3((BL * XDBL_N) / 256), blk, 0, stream>>>(scratch, xdbl, dtlow16);

    // 4) dt = softplus(dt_low @ W_dt + b_dt)   (64-row tile, 1024 blocks)
    gemm_r64<3><<<dim3(DINNER / 128, BL / 64), blk, 0, stream>>>(
        dtlow16, WdtT16, dt16, BL, DINNER, DTRANK, b_dt);

    // 5) chunked scan: pass1 -> combine -> pass3 (+fused gate)
    {
        dim3 grid1(DINNER / 256, BATCH * NCHUNK);
        scan_pass1<<<grid1, blk, 0, stream>>>(dt16, xc16, xdbl, A_log, sums_h, sums_p);
        scan_combine<<<dim3((BATCH * DSTATE * DINNER) / 256), blk, 0, stream>>>(
            sums_h, sums_p);
        scan_pass3<<<grid1, blk, 0, stream>>>(dt16, xc16, xdbl, A_log, xz16,
                                              sums_p, Dp, gated16);
    }
    // 7) out = gated @ W_out   (64-row tile, 512 blocks vs 256 for 128-tile)
    gemm_r64<0><<<dim3(DMODEL / 128, BL / 64), blk, 0, stream>>>(
        gated16, WoT16, out, BL, DMODEL, DINNER, nullptr);

    (void)in_sizes; (void)n_in; (void)out_size; (void)ws_size;
}